// Round 2
// baseline (30640.549 us; speedup 1.0000x reference)
//
#include <hip/hip_runtime.h>

// SentenceEncodingRNN2: 2-layer BiLSTM (T=256,B=128,D=300,H=256) + attention pooling.
// Round 2: fp32, time-chunked xg buffers (ws ~203 MB), bounded spin sync.
//   proj_gemm : xg[s-t0] = X[gather(s)] @ W_ih^T + (b_ih+b_hh); rev dir gathered in scan order
//   lstm_rec  : 64-step chunk, persistent weights in VGPRs, h exchanged among 8-block
//               domains via release/acquire atomics; state in hbuf/cbuf across chunks
//   attn_gemm : scores[m] += sum_e tanh(h2@mlp_w^T + b) * ctx (fused epilogue)
//   attn_final: masked softmax over t + weighted sum -> out[B,512]

#define T_ 256
#define B_ 128
#define D_ 300
#define H_ 256
#define G4H 1024   // 4*H
#define H2 512     // 2*H
#define TC 64      // time-chunk length

// ---------------- helpers ----------------
__device__ __forceinline__ float sigf(float x) { return 1.f / (1.f + __expf(-x)); }
__device__ __forceinline__ float tanhfast(float x) { return 2.f / (1.f + __expf(-2.f * x)) - 1.f; }

// ---------------- projection GEMM (chunked, optional reverse gather) ----------------
// C[lm][n] = sum_k X[srow(lm)][k]*W[n][k] + b1[n]+b2[n],  lm in [0, TC*128)
// srow: global scan-step s = t0 + (lm>>7), b = lm&127;
//       rev ? revidx(s,len_b)*128+b : s*128+b
__global__ __launch_bounds__(256) void proj_gemm(
    const float* __restrict__ X, const float* __restrict__ W,
    const float* __restrict__ bias1, const float* __restrict__ bias2,
    float* __restrict__ C, int N, int K,
    const int* __restrict__ lengths, int rev, int t0)
{
  __shared__ float Xs[16][132];
  __shared__ float Ws[16][132];
  const int tid = threadIdx.x;
  const int tm = tid & 15, tn = tid >> 4;
  const int m0 = blockIdx.y * 128, n0 = blockIdx.x * 128;
  const int cc = tid & 15, r0 = tid >> 4;
  const int s_step = t0 + blockIdx.y;

  int srow[8];
#pragma unroll
  for (int i = 0; i < 8; i++) {
    const int r = r0 + i * 16;          // r == batch index b within tile
    int ss = s_step;
    if (rev) {
      int lb = lengths[r]; if (lb < 1) lb = 1;
      ss = (s_step < lb) ? (lb - 1 - s_step) : s_step;
    }
    srow[i] = ss * 128 + r;
  }

  float acc[8][8];
#pragma unroll
  for (int i = 0; i < 8; i++)
#pragma unroll
    for (int j = 0; j < 8; j++) acc[i][j] = 0.f;

  for (int k0 = 0; k0 < K; k0 += 16) {
    const int k = k0 + cc;
    const bool kin = (k < K);
#pragma unroll
    for (int i = 0; i < 8; i++) {
      const int r = r0 + i * 16;
      Xs[cc][r] = kin ? X[(size_t)srow[i] * K + k] : 0.f;
      Ws[cc][r] = kin ? W[(size_t)(n0 + r) * K + k] : 0.f;
    }
    __syncthreads();
#pragma unroll
    for (int kk = 0; kk < 16; kk++) {
      float a[8], b[8];
      *(float4*)&a[0] = *(const float4*)&Xs[kk][tm * 8];
      *(float4*)&a[4] = *(const float4*)&Xs[kk][tm * 8 + 4];
      *(float4*)&b[0] = *(const float4*)&Ws[kk][tn * 8];
      *(float4*)&b[4] = *(const float4*)&Ws[kk][tn * 8 + 4];
#pragma unroll
      for (int i = 0; i < 8; i++)
#pragma unroll
        for (int j = 0; j < 8; j++) acc[i][j] += a[i] * b[j];
    }
    __syncthreads();
  }

  const int col0 = n0 + tn * 8;
  float bsum[8];
#pragma unroll
  for (int j = 0; j < 8; j++) bsum[j] = bias1[col0 + j] + bias2[col0 + j];
#pragma unroll
  for (int i = 0; i < 8; i++) {
    float* Crow = C + (size_t)(m0 + tm * 8 + i) * N + col0;
    float4 v0, v1;
    v0.x = acc[i][0] + bsum[0]; v0.y = acc[i][1] + bsum[1];
    v0.z = acc[i][2] + bsum[2]; v0.w = acc[i][3] + bsum[3];
    v1.x = acc[i][4] + bsum[4]; v1.y = acc[i][5] + bsum[5];
    v1.z = acc[i][6] + bsum[6]; v1.w = acc[i][7] + bsum[7];
    *(float4*)(Crow) = v0;
    *(float4*)(Crow + 4) = v1;
  }
}

// ---------------- attention score GEMM with fused tanh*ctx epilogue ----------------
__global__ __launch_bounds__(256) void attn_gemm(
    const float* __restrict__ X, const float* __restrict__ W,
    const float* __restrict__ mlp_b, const float* __restrict__ ctx,
    float* __restrict__ scores, int M, int N, int K)
{
  __shared__ float Xs[16][132];
  __shared__ float Ws[16][132];
  __shared__ float red[128][17];
  const int tid = threadIdx.x;
  const int tm = tid & 15, tn = tid >> 4;
  const int m0 = blockIdx.y * 128, n0 = blockIdx.x * 128;
  const int cc = tid & 15, r0 = tid >> 4;
  float acc[8][8];
#pragma unroll
  for (int i = 0; i < 8; i++)
#pragma unroll
    for (int j = 0; j < 8; j++) acc[i][j] = 0.f;

  for (int k0 = 0; k0 < K; k0 += 16) {
    const int k = k0 + cc;
    const bool kin = (k < K);
#pragma unroll
    for (int i = 0; i < 8; i++) {
      const int r = r0 + i * 16;
      Xs[cc][r] = kin ? X[(size_t)(m0 + r) * K + k] : 0.f;
      Ws[cc][r] = kin ? W[(size_t)(n0 + r) * K + k] : 0.f;
    }
    __syncthreads();
#pragma unroll
    for (int kk = 0; kk < 16; kk++) {
      float a[8], b[8];
      *(float4*)&a[0] = *(const float4*)&Xs[kk][tm * 8];
      *(float4*)&a[4] = *(const float4*)&Xs[kk][tm * 8 + 4];
      *(float4*)&b[0] = *(const float4*)&Ws[kk][tn * 8];
      *(float4*)&b[4] = *(const float4*)&Ws[kk][tn * 8 + 4];
#pragma unroll
      for (int i = 0; i < 8; i++)
#pragma unroll
        for (int j = 0; j < 8; j++) acc[i][j] += a[i] * b[j];
    }
    __syncthreads();
  }

  const int col0 = n0 + tn * 8;
  float bb8[8], cc8[8];
#pragma unroll
  for (int j = 0; j < 8; j++) { bb8[j] = mlp_b[col0 + j]; cc8[j] = ctx[col0 + j]; }
#pragma unroll
  for (int i = 0; i < 8; i++) {
    float p = 0.f;
#pragma unroll
    for (int j = 0; j < 8; j++) p += tanhfast(acc[i][j] + bb8[j]) * cc8[j];
    red[tm * 8 + i][tn] = p;
  }
  __syncthreads();
  if (tid < 128) {
    float sum = 0.f;
#pragma unroll
    for (int q = 0; q < 16; q++) sum += red[tid][q];
    atomicAdd(&scores[m0 + tid], sum);
  }
}

// ---------------- LSTM recurrence chunk (both directions) ----------------
// blocks: 256 = d(2) * g(16 batch-groups of 8) * s(8 h-slices of 32)
// thread: tid = hh*8 + kc; owns cell (b = g*8+kc, hdim = s*32+hh)
// xgF/xgR hold TC scan-steps [t0, t0+TC) in scan order.
__global__ __launch_bounds__(256, 1) void lstm_rec(
    const float* __restrict__ xgF, const float* __restrict__ xgR,
    const float* __restrict__ whF, const float* __restrict__ whR,
    const int* __restrict__ lengths, float* __restrict__ hout,
    float* __restrict__ hbuf, float* __restrict__ cbuf,
    int* __restrict__ cnt, int t0)
{
  // ht: h_prev tile [8 batches][256], chunk-padded: addr(bb,k)=bb*288+(k>>5)*36+(k&31)
  __shared__ float ht[2304];
  const int tid = threadIdx.x;
  const int blk = blockIdx.x;
  const int d = blk >> 7;
  const int g = (blk >> 3) & 15;
  const int s = blk & 7;
  const int hh = tid >> 3;
  const int kc = tid & 7;
  const int b = g * 8 + kc;
  const int hdim = s * 32 + hh;
  const float* __restrict__ xg = d ? xgR : xgF;
  const float* __restrict__ wh = d ? whR : whF;

  float wreg[4][32];
#pragma unroll
  for (int gate = 0; gate < 4; gate++) {
    const float* wrow = wh + ((size_t)(gate * 256 + hdim)) * 256 + kc * 32;
#pragma unroll
    for (int j = 0; j < 32; j += 4) {
      float4 v = *(const float4*)(wrow + j);
      wreg[gate][j] = v.x; wreg[gate][j + 1] = v.y;
      wreg[gate][j + 2] = v.z; wreg[gate][j + 3] = v.w;
    }
  }

  float c;
  if (t0 == 0) {
    for (int i = tid; i < 2304; i += 256) ht[i] = 0.f;
    c = 0.f;
  } else {
    // load h(t0-1) tile from hbuf parity slot t0&1, c from cbuf
    const int ph0 = t0 & 1;
    const int fi = tid * 8;
    const int b2 = fi >> 8, k2 = fi & 255;
    const float* src = hbuf + ((size_t)(ph0 * 2 + d) * 128 + g * 8 + b2) * 256 + k2;
    float4 v0 = *(const float4*)(src);
    float4 v1 = *(const float4*)(src + 4);
    float* dst = ht + b2 * 288 + ((k2 >> 5) * 36) + (k2 & 31);
    *(float4*)dst = v0;
    *(float4*)(dst + 4) = v1;
    c = cbuf[((size_t)d * 128 + b) * 256 + hdim];
  }
  int lb = lengths[b]; if (lb < 1) lb = 1;
  const int cntbase = d * 16 + g;
  __syncthreads();

  const int tend = t0 + TC;
  for (int t = t0; t < tend; t++) {
    const int tin = d ? ((t < lb) ? (lb - 1 - t) : t) : t;
    // input-projection gates for owned cell (scan-order chunk layout)
    const float* xr = xg + ((size_t)(t - t0) * 128 + b) * 1024 + hdim;
    const float x0 = xr[0], x1 = xr[256], x2 = xr[512], x3 = xr[768];

    float part[4][8];
#pragma unroll
    for (int gate = 0; gate < 4; gate++)
#pragma unroll
      for (int bb = 0; bb < 8; bb++) part[gate][bb] = 0.f;

#pragma unroll
    for (int bb = 0; bb < 8; bb++) {
      const float* hrow = ht + bb * 288 + kc * 36;
#pragma unroll
      for (int j = 0; j < 32; j += 4) {
        float4 h4 = *(const float4*)(hrow + j);
#pragma unroll
        for (int gate = 0; gate < 4; gate++) {
          part[gate][bb] += h4.x * wreg[gate][j]     + h4.y * wreg[gate][j + 1]
                          + h4.z * wreg[gate][j + 2] + h4.w * wreg[gate][j + 3];
        }
      }
    }

    // halving butterfly over kc: after 3 rounds lane kc holds full sum for bb==kc
    float n4[4][4];
#pragma unroll
    for (int gate = 0; gate < 4; gate++)
#pragma unroll
      for (int q = 0; q < 4; q++) {
        const float keep = (kc & 4) ? part[gate][q + 4] : part[gate][q];
        const float send = (kc & 4) ? part[gate][q]     : part[gate][q + 4];
        n4[gate][q] = keep + __shfl_xor(send, 4, 8);
      }
    float n2[4][2];
#pragma unroll
    for (int gate = 0; gate < 4; gate++)
#pragma unroll
      for (int q = 0; q < 2; q++) {
        const float keep = (kc & 2) ? n4[gate][q + 2] : n4[gate][q];
        const float send = (kc & 2) ? n4[gate][q]     : n4[gate][q + 2];
        n2[gate][q] = keep + __shfl_xor(send, 2, 8);
      }
    float gsum[4];
#pragma unroll
    for (int gate = 0; gate < 4; gate++) {
      const float keep = (kc & 1) ? n2[gate][1] : n2[gate][0];
      const float send = (kc & 1) ? n2[gate][0] : n2[gate][1];
      gsum[gate] = keep + __shfl_xor(send, 1, 8);
    }

    const float si = sigf(gsum[0] + x0);
    const float sf = sigf(gsum[1] + x1);
    const float tg = tanhfast(gsum[2] + x2);
    const float so = sigf(gsum[3] + x3);
    c = sf * c + si * tg;
    const float h = so * tanhfast(c);

    hout[((size_t)tin * 128 + b) * 512 + d * 256 + hdim] = h;

    // publish h for next step (last chunk-step's write feeds the next launch)
    const int ph = (t + 1) & 1;
    hbuf[((size_t)(ph * 2 + d) * 128 + b) * 256 + hdim] = h;

    if (t < tend - 1) {
      __threadfence();          // release peers' view of hbuf
      __syncthreads();
      if (tid == 0) {
        int* cp = cnt + t * 32 + cntbase;
        __hip_atomic_fetch_add(cp, 1, __ATOMIC_RELEASE, __HIP_MEMORY_SCOPE_AGENT);
        int it = 0;
        while (__hip_atomic_load(cp, __ATOMIC_ACQUIRE, __HIP_MEMORY_SCOPE_AGENT) < 8) {
          __builtin_amdgcn_s_sleep(2);
          if (++it > 40000) break;   // bounded: failure -> visible absmax, not hang
        }
      }
      __syncthreads();
      __threadfence();          // acquire side
      const int fi = tid * 8;
      const int b2 = fi >> 8, k2 = fi & 255;
      const float* src = hbuf + ((size_t)(ph * 2 + d) * 128 + g * 8 + b2) * 256 + k2;
      float4 v0 = *(const float4*)(src);
      float4 v1 = *(const float4*)(src + 4);
      float* dst = ht + b2 * 288 + ((k2 >> 5) * 36) + (k2 & 31);
      *(float4*)dst = v0;
      *(float4*)(dst + 4) = v1;
      __syncthreads();
    }
  }
  // persist c for next chunk
  cbuf[((size_t)d * 128 + b) * 256 + hdim] = c;
}

// ---------------- masked softmax over t + weighted sum ----------------
__global__ __launch_bounds__(256) void attn_final(
    const float* __restrict__ h2, const float* __restrict__ scores,
    const int* __restrict__ lengths, float* __restrict__ out)
{
  __shared__ float sl[256];
  __shared__ float red[256];
  const int b = blockIdx.x, tid = threadIdx.x;
  int lb = lengths[b]; if (lb < 1) lb = 1;
  const float sc = scores[(size_t)tid * 128 + b];
  const bool valid = (tid < lb);
  red[tid] = valid ? sc : -1e30f;
  __syncthreads();
  for (int off = 128; off > 0; off >>= 1) {
    if (tid < off) red[tid] = fmaxf(red[tid], red[tid + off]);
    __syncthreads();
  }
  const float mx = red[0];
  __syncthreads();
  const float p = valid ? __expf(sc - mx) : 0.f;
  red[tid] = p;
  __syncthreads();
  for (int off = 128; off > 0; off >>= 1) {
    if (tid < off) red[tid] += red[tid + off];
    __syncthreads();
  }
  const float inv = 1.f / red[0];
  __syncthreads();
  sl[tid] = p * inv;
  __syncthreads();

  float ax = 0.f, ay = 0.f;
  const int dd = tid * 2;
  for (int t = 0; t < 256; t++) {
    const float w = sl[t];
    if (w != 0.f) {  // wave-uniform
      const float* row = h2 + ((size_t)t * 128 + b) * 512 + dd;
      ax += w * row[0];
      ay += w * row[1];
    }
  }
  float2 r; r.x = ax; r.y = ay;
  *(float2*)(out + (size_t)b * 512 + dd) = r;
}

// ---------------- launch ----------------
extern "C" void kernel_launch(void* const* d_in, const int* in_sizes, int n_in,
                              void* d_out, int out_size, void* d_ws, size_t ws_size,
                              hipStream_t stream) {
  (void)in_sizes; (void)n_in; (void)out_size; (void)ws_size;
  const float* x        = (const float*)d_in[0];
  const int*   lengths  = (const int*)d_in[1];
  const float* w_ih_l0  = (const float*)d_in[2];
  const float* w_hh_l0  = (const float*)d_in[3];
  const float* b_ih_l0  = (const float*)d_in[4];
  const float* b_hh_l0  = (const float*)d_in[5];
  const float* w_ih_l0r = (const float*)d_in[6];
  const float* w_hh_l0r = (const float*)d_in[7];
  const float* b_ih_l0r = (const float*)d_in[8];
  const float* b_hh_l0r = (const float*)d_in[9];
  const float* w_ih_l1  = (const float*)d_in[10];
  const float* w_hh_l1  = (const float*)d_in[11];
  const float* b_ih_l1  = (const float*)d_in[12];
  const float* b_hh_l1  = (const float*)d_in[13];
  const float* w_ih_l1r = (const float*)d_in[14];
  const float* w_hh_l1r = (const float*)d_in[15];
  const float* b_ih_l1r = (const float*)d_in[16];
  const float* b_hh_l1r = (const float*)d_in[17];
  const float* mlp_w    = (const float*)d_in[18];
  const float* mlp_b    = (const float*)d_in[19];
  const float* ctx      = (const float*)d_in[20];
  float* out = (float*)d_out;

  // workspace layout (floats): total 50,642,944 floats = 202.6 MB
  float* ws = (float*)d_ws;
  const size_t XGC = (size_t)TC * B_ * G4H;          // 8,388,608
  const size_t H_SZ = (size_t)T_ * B_ * H2;          // 16,777,216
  float* xgA    = ws;
  float* xgB    = xgA + XGC;
  float* h1     = xgB + XGC;
  float* h2     = h1 + H_SZ;
  float* hbuf   = h2 + H_SZ;                          // 131,072
  float* cbuf   = hbuf + 131072;                      // 131,072
  float* scores = cbuf + 131072;                      // 32,768
  int*   flags  = (int*)(scores + 32768);             // 16,384 ints

  hipMemsetAsync(scores, 0, (size_t)(32768 + 16384) * 4, stream);

  dim3 blk(256);
  const dim3 pgrid(G4H / 128, TC);   // (8, 64)

  // layer 0 (K=300), chunked over time
  for (int c = 0; c < T_ / TC; c++) {
    const int t0 = c * TC;
    proj_gemm<<<pgrid, blk, 0, stream>>>(x, w_ih_l0,  b_ih_l0,  b_hh_l0,  xgA, G4H, D_, lengths, 0, t0);
    proj_gemm<<<pgrid, blk, 0, stream>>>(x, w_ih_l0r, b_ih_l0r, b_hh_l0r, xgB, G4H, D_, lengths, 1, t0);
    lstm_rec<<<256, blk, 0, stream>>>(xgA, xgB, w_hh_l0, w_hh_l0r, lengths, h1, hbuf, cbuf, flags, t0);
  }
  // layer 1 (K=512)
  for (int c = 0; c < T_ / TC; c++) {
    const int t0 = c * TC;
    proj_gemm<<<pgrid, blk, 0, stream>>>(h1, w_ih_l1,  b_ih_l1,  b_hh_l1,  xgA, G4H, H2, lengths, 0, t0);
    proj_gemm<<<pgrid, blk, 0, stream>>>(h1, w_ih_l1r, b_ih_l1r, b_hh_l1r, xgB, G4H, H2, lengths, 1, t0);
    lstm_rec<<<256, blk, 0, stream>>>(xgA, xgB, w_hh_l1, w_hh_l1r, lengths, h2, hbuf, cbuf, flags + 8192, t0);
  }
  // attention
  attn_gemm<<<dim3(H2 / 128, (T_ * B_) / 128), blk, 0, stream>>>(h2, mlp_w, mlp_b, ctx, scores, T_ * B_, H2, H2);
  attn_final<<<B_, blk, 0, stream>>>(h2, scores, lengths, out);
}

// Round 3
// 7499.000 us; speedup vs baseline: 4.0860x; 4.0860x over previous
//
#include <hip/hip_runtime.h>

// SentenceEncodingRNN2: 2-layer BiLSTM (T=256,B=128,D=300,H=256) + attention pooling.
// Round 3: replace fence-heavy sync in lstm_rec with RELAXED agent-scope atomics.
//   Rationale: __threadfence / acquire-release atomics emit buffer_wbl2/buffer_inv
//   (full per-XCD L2 writeback/invalidate) on gfx950 -> ~52us/step observed.
//   Relaxed device-scope atomics compile to sc0sc1 loads/stores (bypass L1/L2,
//   served at the coherent point) with NO cache maintenance; ordering between the
//   h-data stores and the flag RMW comes from the s_waitcnt vmcnt(0) that
//   __syncthreads() emits.

#define T_ 256
#define B_ 128
#define D_ 300
#define H_ 256
#define G4H 1024   // 4*H
#define H2 512     // 2*H
#define TC 64      // time-chunk length

// ---------------- helpers ----------------
__device__ __forceinline__ float sigf(float x) { return 1.f / (1.f + __expf(-x)); }
__device__ __forceinline__ float tanhfast(float x) { return 2.f / (1.f + __expf(-2.f * x)) - 1.f; }

// ---------------- projection GEMM (chunked, optional reverse gather) ----------------
__global__ __launch_bounds__(256) void proj_gemm(
    const float* __restrict__ X, const float* __restrict__ W,
    const float* __restrict__ bias1, const float* __restrict__ bias2,
    float* __restrict__ C, int N, int K,
    const int* __restrict__ lengths, int rev, int t0)
{
  __shared__ float Xs[16][132];
  __shared__ float Ws[16][132];
  const int tid = threadIdx.x;
  const int tm = tid & 15, tn = tid >> 4;
  const int m0 = blockIdx.y * 128, n0 = blockIdx.x * 128;
  const int cc = tid & 15, r0 = tid >> 4;
  const int s_step = t0 + blockIdx.y;

  int srow[8];
#pragma unroll
  for (int i = 0; i < 8; i++) {
    const int r = r0 + i * 16;          // r == batch index b within tile
    int ss = s_step;
    if (rev) {
      int lb = lengths[r]; if (lb < 1) lb = 1;
      ss = (s_step < lb) ? (lb - 1 - s_step) : s_step;
    }
    srow[i] = ss * 128 + r;
  }

  float acc[8][8];
#pragma unroll
  for (int i = 0; i < 8; i++)
#pragma unroll
    for (int j = 0; j < 8; j++) acc[i][j] = 0.f;

  for (int k0 = 0; k0 < K; k0 += 16) {
    const int k = k0 + cc;
    const bool kin = (k < K);
#pragma unroll
    for (int i = 0; i < 8; i++) {
      const int r = r0 + i * 16;
      Xs[cc][r] = kin ? X[(size_t)srow[i] * K + k] : 0.f;
      Ws[cc][r] = kin ? W[(size_t)(n0 + r) * K + k] : 0.f;
    }
    __syncthreads();
#pragma unroll
    for (int kk = 0; kk < 16; kk++) {
      float a[8], b[8];
      *(float4*)&a[0] = *(const float4*)&Xs[kk][tm * 8];
      *(float4*)&a[4] = *(const float4*)&Xs[kk][tm * 8 + 4];
      *(float4*)&b[0] = *(const float4*)&Ws[kk][tn * 8];
      *(float4*)&b[4] = *(const float4*)&Ws[kk][tn * 8 + 4];
#pragma unroll
      for (int i = 0; i < 8; i++)
#pragma unroll
        for (int j = 0; j < 8; j++) acc[i][j] += a[i] * b[j];
    }
    __syncthreads();
  }

  const int col0 = n0 + tn * 8;
  float bsum[8];
#pragma unroll
  for (int j = 0; j < 8; j++) bsum[j] = bias1[col0 + j] + bias2[col0 + j];
#pragma unroll
  for (int i = 0; i < 8; i++) {
    float* Crow = C + (size_t)(m0 + tm * 8 + i) * N + col0;
    float4 v0, v1;
    v0.x = acc[i][0] + bsum[0]; v0.y = acc[i][1] + bsum[1];
    v0.z = acc[i][2] + bsum[2]; v0.w = acc[i][3] + bsum[3];
    v1.x = acc[i][4] + bsum[4]; v1.y = acc[i][5] + bsum[5];
    v1.z = acc[i][6] + bsum[6]; v1.w = acc[i][7] + bsum[7];
    *(float4*)(Crow) = v0;
    *(float4*)(Crow + 4) = v1;
  }
}

// ---------------- attention score GEMM with fused tanh*ctx epilogue ----------------
__global__ __launch_bounds__(256) void attn_gemm(
    const float* __restrict__ X, const float* __restrict__ W,
    const float* __restrict__ mlp_b, const float* __restrict__ ctx,
    float* __restrict__ scores, int M, int N, int K)
{
  __shared__ float Xs[16][132];
  __shared__ float Ws[16][132];
  __shared__ float red[128][17];
  const int tid = threadIdx.x;
  const int tm = tid & 15, tn = tid >> 4;
  const int m0 = blockIdx.y * 128, n0 = blockIdx.x * 128;
  const int cc = tid & 15, r0 = tid >> 4;
  float acc[8][8];
#pragma unroll
  for (int i = 0; i < 8; i++)
#pragma unroll
    for (int j = 0; j < 8; j++) acc[i][j] = 0.f;

  for (int k0 = 0; k0 < K; k0 += 16) {
    const int k = k0 + cc;
    const bool kin = (k < K);
#pragma unroll
    for (int i = 0; i < 8; i++) {
      const int r = r0 + i * 16;
      Xs[cc][r] = kin ? X[(size_t)(m0 + r) * K + k] : 0.f;
      Ws[cc][r] = kin ? W[(size_t)(n0 + r) * K + k] : 0.f;
    }
    __syncthreads();
#pragma unroll
    for (int kk = 0; kk < 16; kk++) {
      float a[8], b[8];
      *(float4*)&a[0] = *(const float4*)&Xs[kk][tm * 8];
      *(float4*)&a[4] = *(const float4*)&Xs[kk][tm * 8 + 4];
      *(float4*)&b[0] = *(const float4*)&Ws[kk][tn * 8];
      *(float4*)&b[4] = *(const float4*)&Ws[kk][tn * 8 + 4];
#pragma unroll
      for (int i = 0; i < 8; i++)
#pragma unroll
        for (int j = 0; j < 8; j++) acc[i][j] += a[i] * b[j];
    }
    __syncthreads();
  }

  const int col0 = n0 + tn * 8;
  float bb8[8], cc8[8];
#pragma unroll
  for (int j = 0; j < 8; j++) { bb8[j] = mlp_b[col0 + j]; cc8[j] = ctx[col0 + j]; }
#pragma unroll
  for (int i = 0; i < 8; i++) {
    float p = 0.f;
#pragma unroll
    for (int j = 0; j < 8; j++) p += tanhfast(acc[i][j] + bb8[j]) * cc8[j];
    red[tm * 8 + i][tn] = p;
  }
  __syncthreads();
  if (tid < 128) {
    float sum = 0.f;
#pragma unroll
    for (int q = 0; q < 16; q++) sum += red[tid][q];
    atomicAdd(&scores[m0 + tid], sum);
  }
}

// ---------------- LSTM recurrence chunk (both directions) ----------------
// blocks: 256 = d(2) * g(16 batch-groups of 8) * s(8 h-slices of 32)
// thread: tid = hh*8 + kc; owns cell (b = g*8+kc, hdim = s*32+hh)
__global__ __launch_bounds__(256, 1) void lstm_rec(
    const float* __restrict__ xgF, const float* __restrict__ xgR,
    const float* __restrict__ whF, const float* __restrict__ whR,
    const int* __restrict__ lengths, float* __restrict__ hout,
    float* __restrict__ hbuf, float* __restrict__ cbuf,
    int* __restrict__ cnt, int t0)
{
  // ht: h_prev tile [8 batches][256], chunk-padded: addr(bb,k)=bb*288+(k>>5)*36+(k&31)
  __shared__ float ht[2304];
  const int tid = threadIdx.x;
  const int blk = blockIdx.x;
  const int d = blk >> 7;
  const int g = (blk >> 3) & 15;
  const int s = blk & 7;
  const int hh = tid >> 3;
  const int kc = tid & 7;
  const int b = g * 8 + kc;
  const int hdim = s * 32 + hh;
  const float* __restrict__ xg = d ? xgR : xgF;
  const float* __restrict__ wh = d ? whR : whF;

  float wreg[4][32];
#pragma unroll
  for (int gate = 0; gate < 4; gate++) {
    const float* wrow = wh + ((size_t)(gate * 256 + hdim)) * 256 + kc * 32;
#pragma unroll
    for (int j = 0; j < 32; j += 4) {
      float4 v = *(const float4*)(wrow + j);
      wreg[gate][j] = v.x; wreg[gate][j + 1] = v.y;
      wreg[gate][j + 2] = v.z; wreg[gate][j + 3] = v.w;
    }
  }

  float c;
  if (t0 == 0) {
    for (int i = tid; i < 2304; i += 256) ht[i] = 0.f;
    c = 0.f;
  } else {
    // load h(t0-1) tile from hbuf parity slot t0&1, c from cbuf (kernel boundary = sync)
    const int ph0 = t0 & 1;
    const int fi = tid * 8;
    const int b2 = fi >> 8, k2 = fi & 255;
    const float* src = hbuf + ((size_t)(ph0 * 2 + d) * 128 + g * 8 + b2) * 256 + k2;
    float4 v0 = *(const float4*)(src);
    float4 v1 = *(const float4*)(src + 4);
    float* dst = ht + b2 * 288 + ((k2 >> 5) * 36) + (k2 & 31);
    *(float4*)dst = v0;
    *(float4*)(dst + 4) = v1;
    c = cbuf[((size_t)d * 128 + b) * 256 + hdim];
  }
  int lb = lengths[b]; if (lb < 1) lb = 1;
  const int cntbase = d * 16 + g;
  __syncthreads();

  const int tend = t0 + TC;
  for (int t = t0; t < tend; t++) {
    const int tin = d ? ((t < lb) ? (lb - 1 - t) : t) : t;
    const float* xr = xg + ((size_t)(t - t0) * 128 + b) * 1024 + hdim;
    const float x0 = xr[0], x1 = xr[256], x2 = xr[512], x3 = xr[768];

    float part[4][8];
#pragma unroll
    for (int gate = 0; gate < 4; gate++)
#pragma unroll
      for (int bb = 0; bb < 8; bb++) part[gate][bb] = 0.f;

#pragma unroll
    for (int bb = 0; bb < 8; bb++) {
      const float* hrow = ht + bb * 288 + kc * 36;
#pragma unroll
      for (int j = 0; j < 32; j += 4) {
        float4 h4 = *(const float4*)(hrow + j);
#pragma unroll
        for (int gate = 0; gate < 4; gate++) {
          part[gate][bb] += h4.x * wreg[gate][j]     + h4.y * wreg[gate][j + 1]
                          + h4.z * wreg[gate][j + 2] + h4.w * wreg[gate][j + 3];
        }
      }
    }

    // halving butterfly over kc: after 3 rounds lane kc holds full sum for bb==kc
    float n4[4][4];
#pragma unroll
    for (int gate = 0; gate < 4; gate++)
#pragma unroll
      for (int q = 0; q < 4; q++) {
        const float keep = (kc & 4) ? part[gate][q + 4] : part[gate][q];
        const float send = (kc & 4) ? part[gate][q]     : part[gate][q + 4];
        n4[gate][q] = keep + __shfl_xor(send, 4, 8);
      }
    float n2[4][2];
#pragma unroll
    for (int gate = 0; gate < 4; gate++)
#pragma unroll
      for (int q = 0; q < 2; q++) {
        const float keep = (kc & 2) ? n4[gate][q + 2] : n4[gate][q];
        const float send = (kc & 2) ? n4[gate][q]     : n4[gate][q + 2];
        n2[gate][q] = keep + __shfl_xor(send, 2, 8);
      }
    float gsum[4];
#pragma unroll
    for (int gate = 0; gate < 4; gate++) {
      const float keep = (kc & 1) ? n2[gate][1] : n2[gate][0];
      const float send = (kc & 1) ? n2[gate][0] : n2[gate][1];
      gsum[gate] = keep + __shfl_xor(send, 1, 8);
    }

    const float si = sigf(gsum[0] + x0);
    const float sf = sigf(gsum[1] + x1);
    const float tg = tanhfast(gsum[2] + x2);
    const float so = sigf(gsum[3] + x3);
    c = sf * c + si * tg;
    const float h = so * tanhfast(c);

    hout[((size_t)tin * 128 + b) * 512 + d * 256 + hdim] = h;

    // publish h for next step: RELAXED agent-scope store (sc0sc1, bypasses caches,
    // lands at the coherent point; NO wbl2/inv cache maintenance).
    const int ph = (t + 1) & 1;
    __hip_atomic_store(&hbuf[((size_t)(ph * 2 + d) * 128 + b) * 256 + hdim], h,
                       __ATOMIC_RELAXED, __HIP_MEMORY_SCOPE_AGENT);

    if (t < tend - 1) {
      // __syncthreads() emits s_waitcnt vmcnt(0) -> hbuf stores are globally
      // visible before any thread signals the flag.
      __syncthreads();
      if (tid == 0) {
        int* cp = cnt + t * 32 + cntbase;
        __hip_atomic_fetch_add(cp, 1, __ATOMIC_RELAXED, __HIP_MEMORY_SCOPE_AGENT);
        int it = 0;
        while (__hip_atomic_load(cp, __ATOMIC_RELAXED, __HIP_MEMORY_SCOPE_AGENT) < 8) {
          __builtin_amdgcn_s_sleep(1);
          if (++it > 50000) break;   // bounded: failure -> visible absmax, not hang
        }
      }
      __syncthreads();
      // gather peers' h: RELAXED agent-scope loads bypass (possibly stale) L1/L2.
      const int bb = tid >> 5, kbase = tid & 31;
      const float* src = hbuf + ((size_t)(ph * 2 + d) * 128 + g * 8 + bb) * 256;
      float vals[8];
#pragma unroll
      for (int j = 0; j < 8; j++)
        vals[j] = __hip_atomic_load(&src[kbase + 32 * j],
                                    __ATOMIC_RELAXED, __HIP_MEMORY_SCOPE_AGENT);
#pragma unroll
      for (int j = 0; j < 8; j++) ht[bb * 288 + j * 36 + kbase] = vals[j];
      __syncthreads();
    }
  }
  // persist c for next chunk
  cbuf[((size_t)d * 128 + b) * 256 + hdim] = c;
}

// ---------------- masked softmax over t + weighted sum ----------------
__global__ __launch_bounds__(256) void attn_final(
    const float* __restrict__ h2, const float* __restrict__ scores,
    const int* __restrict__ lengths, float* __restrict__ out)
{
  __shared__ float sl[256];
  __shared__ float red[256];
  const int b = blockIdx.x, tid = threadIdx.x;
  int lb = lengths[b]; if (lb < 1) lb = 1;
  const float sc = scores[(size_t)tid * 128 + b];
  const bool valid = (tid < lb);
  red[tid] = valid ? sc : -1e30f;
  __syncthreads();
  for (int off = 128; off > 0; off >>= 1) {
    if (tid < off) red[tid] = fmaxf(red[tid], red[tid + off]);
    __syncthreads();
  }
  const float mx = red[0];
  __syncthreads();
  const float p = valid ? __expf(sc - mx) : 0.f;
  red[tid] = p;
  __syncthreads();
  for (int off = 128; off > 0; off >>= 1) {
    if (tid < off) red[tid] += red[tid + off];
    __syncthreads();
  }
  const float inv = 1.f / red[0];
  __syncthreads();
  sl[tid] = p * inv;
  __syncthreads();

  float ax = 0.f, ay = 0.f;
  const int dd = tid * 2;
  for (int t = 0; t < 256; t++) {
    const float w = sl[t];
    if (w != 0.f) {  // wave-uniform
      const float* row = h2 + ((size_t)t * 128 + b) * 512 + dd;
      ax += w * row[0];
      ay += w * row[1];
    }
  }
  float2 r; r.x = ax; r.y = ay;
  *(float2*)(out + (size_t)b * 512 + dd) = r;
}

// ---------------- launch ----------------
extern "C" void kernel_launch(void* const* d_in, const int* in_sizes, int n_in,
                              void* d_out, int out_size, void* d_ws, size_t ws_size,
                              hipStream_t stream) {
  (void)in_sizes; (void)n_in; (void)out_size; (void)ws_size;
  const float* x        = (const float*)d_in[0];
  const int*   lengths  = (const int*)d_in[1];
  const float* w_ih_l0  = (const float*)d_in[2];
  const float* w_hh_l0  = (const float*)d_in[3];
  const float* b_ih_l0  = (const float*)d_in[4];
  const float* b_hh_l0  = (const float*)d_in[5];
  const float* w_ih_l0r = (const float*)d_in[6];
  const float* w_hh_l0r = (const float*)d_in[7];
  const float* b_ih_l0r = (const float*)d_in[8];
  const float* b_hh_l0r = (const float*)d_in[9];
  const float* w_ih_l1  = (const float*)d_in[10];
  const float* w_hh_l1  = (const float*)d_in[11];
  const float* b_ih_l1  = (const float*)d_in[12];
  const float* b_hh_l1  = (const float*)d_in[13];
  const float* w_ih_l1r = (const float*)d_in[14];
  const float* w_hh_l1r = (const float*)d_in[15];
  const float* b_ih_l1r = (const float*)d_in[16];
  const float* b_hh_l1r = (const float*)d_in[17];
  const float* mlp_w    = (const float*)d_in[18];
  const float* mlp_b    = (const float*)d_in[19];
  const float* ctx      = (const float*)d_in[20];
  float* out = (float*)d_out;

  // workspace layout (floats): total ~202.6 MB
  float* ws = (float*)d_ws;
  const size_t XGC = (size_t)TC * B_ * G4H;          // 8,388,608
  const size_t H_SZ = (size_t)T_ * B_ * H2;          // 16,777,216
  float* xgA    = ws;
  float* xgB    = xgA + XGC;
  float* h1     = xgB + XGC;
  float* h2     = h1 + H_SZ;
  float* hbuf   = h2 + H_SZ;                          // 131,072
  float* cbuf   = hbuf + 131072;                      // 131,072
  float* scores = cbuf + 131072;                      // 32,768
  int*   flags  = (int*)(scores + 32768);             // 16,384 ints

  hipMemsetAsync(scores, 0, (size_t)(32768 + 16384) * 4, stream);

  dim3 blk(256);
  const dim3 pgrid(G4H / 128, TC);   // (8, 64)

  // layer 0 (K=300), chunked over time
  for (int c = 0; c < T_ / TC; c++) {
    const int t0 = c * TC;
    proj_gemm<<<pgrid, blk, 0, stream>>>(x, w_ih_l0,  b_ih_l0,  b_hh_l0,  xgA, G4H, D_, lengths, 0, t0);
    proj_gemm<<<pgrid, blk, 0, stream>>>(x, w_ih_l0r, b_ih_l0r, b_hh_l0r, xgB, G4H, D_, lengths, 1, t0);
    lstm_rec<<<256, blk, 0, stream>>>(xgA, xgB, w_hh_l0, w_hh_l0r, lengths, h1, hbuf, cbuf, flags, t0);
  }
  // layer 1 (K=512)
  for (int c = 0; c < T_ / TC; c++) {
    const int t0 = c * TC;
    proj_gemm<<<pgrid, blk, 0, stream>>>(h1, w_ih_l1,  b_ih_l1,  b_hh_l1,  xgA, G4H, H2, lengths, 0, t0);
    proj_gemm<<<pgrid, blk, 0, stream>>>(h1, w_ih_l1r, b_ih_l1r, b_hh_l1r, xgB, G4H, H2, lengths, 1, t0);
    lstm_rec<<<256, blk, 0, stream>>>(xgA, xgB, w_hh_l1, w_hh_l1r, lengths, h2, hbuf, cbuf, flags + 8192, t0);
  }
  // attention
  attn_gemm<<<dim3(H2 / 128, (T_ * B_) / 128), blk, 0, stream>>>(h2, mlp_w, mlp_b, ctx, scores, T_ * B_, H2, H2);
  attn_final<<<B_, blk, 0, stream>>>(h2, scores, lengths, out);
}

// Round 4
// 7330.676 us; speedup vs baseline: 4.1798x; 1.0230x over previous
//
#include <hip/hip_runtime.h>

// SentenceEncodingRNN2: 2-layer BiLSTM (T=256,B=128,D=300,H=256) + attention pooling.
// Round 4: sync-path surgery in lstm_rec (2 barriers/step, distributed unsigned poll,
//          xg prefetch under sync) + register-double-buffered proj_gemm.
//   R3 counters: step=10.3us = VALU 2.4 + LDS 1.3 + ~6us sync (3 barriers, leader
//   sleep-poll, exposed xg loads). Poisoned-flag rocprof replays spun to cap ->
//   31-41ms ghost dispatches; unsigned >=8 poll free-passes garbage instead.

#define T_ 256
#define B_ 128
#define D_ 300
#define H_ 256
#define G4H 1024   // 4*H
#define H2 512     // 2*H
#define TC 64      // time-chunk length

// ---------------- helpers ----------------
__device__ __forceinline__ float sigf(float x) { return 1.f / (1.f + __expf(-x)); }
__device__ __forceinline__ float tanhfast(float x) { return 2.f / (1.f + __expf(-2.f * x)) - 1.f; }

// ---------------- projection GEMM (chunked, optional reverse gather) ----------------
// C[lm][n] = sum_k X[srow(lm)][k]*W[n][k] + b1[n]+b2[n]
// Register double-buffer: next 16-deep k-tile loads issue while current computes.
__global__ __launch_bounds__(256) void proj_gemm(
    const float* __restrict__ X, const float* __restrict__ W,
    const float* __restrict__ bias1, const float* __restrict__ bias2,
    float* __restrict__ C, int N, int K,
    const int* __restrict__ lengths, int rev, int t0)
{
  __shared__ float Xs[16][132];
  __shared__ float Ws[16][132];
  const int tid = threadIdx.x;
  const int tm = tid & 15, tn = tid >> 4;
  const int m0 = blockIdx.y * 128, n0 = blockIdx.x * 128;
  const int cc = tid & 15, r0 = tid >> 4;
  const int s_step = t0 + blockIdx.y;

  int srow[8];
#pragma unroll
  for (int i = 0; i < 8; i++) {
    const int r = r0 + i * 16;          // r == batch index b within tile
    int ss = s_step;
    if (rev) {
      int lb = lengths[r]; if (lb < 1) lb = 1;
      ss = (s_step < lb) ? (lb - 1 - s_step) : s_step;
    }
    srow[i] = ss * 128 + r;
  }

  float acc[8][8];
#pragma unroll
  for (int i = 0; i < 8; i++)
#pragma unroll
    for (int j = 0; j < 8; j++) acc[i][j] = 0.f;

  float rx[8], rw[8];
  {
    const int k = cc;
    const bool kin = (k < K);
#pragma unroll
    for (int i = 0; i < 8; i++) {
      const int r = r0 + i * 16;
      rx[i] = kin ? X[(size_t)srow[i] * K + k] : 0.f;
      rw[i] = kin ? W[(size_t)(n0 + r) * K + k] : 0.f;
    }
  }

  for (int k0 = 0; k0 < K; k0 += 16) {
#pragma unroll
    for (int i = 0; i < 8; i++) {
      const int r = r0 + i * 16;
      Xs[cc][r] = rx[i];
      Ws[cc][r] = rw[i];
    }
    __syncthreads();
    if (k0 + 16 < K) {
      const int k = k0 + 16 + cc;
      const bool kin = (k < K);
#pragma unroll
      for (int i = 0; i < 8; i++) {
        const int r = r0 + i * 16;
        rx[i] = kin ? X[(size_t)srow[i] * K + k] : 0.f;
        rw[i] = kin ? W[(size_t)(n0 + r) * K + k] : 0.f;
      }
    }
#pragma unroll
    for (int kk = 0; kk < 16; kk++) {
      float a[8], bv[8];
      *(float4*)&a[0] = *(const float4*)&Xs[kk][tm * 8];
      *(float4*)&a[4] = *(const float4*)&Xs[kk][tm * 8 + 4];
      *(float4*)&bv[0] = *(const float4*)&Ws[kk][tn * 8];
      *(float4*)&bv[4] = *(const float4*)&Ws[kk][tn * 8 + 4];
#pragma unroll
      for (int i = 0; i < 8; i++)
#pragma unroll
        for (int j = 0; j < 8; j++) acc[i][j] += a[i] * bv[j];
    }
    __syncthreads();
  }

  const int col0 = n0 + tn * 8;
  float bsum[8];
#pragma unroll
  for (int j = 0; j < 8; j++) bsum[j] = bias1[col0 + j] + bias2[col0 + j];
#pragma unroll
  for (int i = 0; i < 8; i++) {
    float* Crow = C + (size_t)(m0 + tm * 8 + i) * N + col0;
    float4 v0, v1;
    v0.x = acc[i][0] + bsum[0]; v0.y = acc[i][1] + bsum[1];
    v0.z = acc[i][2] + bsum[2]; v0.w = acc[i][3] + bsum[3];
    v1.x = acc[i][4] + bsum[4]; v1.y = acc[i][5] + bsum[5];
    v1.z = acc[i][6] + bsum[6]; v1.w = acc[i][7] + bsum[7];
    *(float4*)(Crow) = v0;
    *(float4*)(Crow + 4) = v1;
  }
}

// ---------------- attention score GEMM with fused tanh*ctx epilogue ----------------
__global__ __launch_bounds__(256) void attn_gemm(
    const float* __restrict__ X, const float* __restrict__ W,
    const float* __restrict__ mlp_b, const float* __restrict__ ctx,
    float* __restrict__ scores, int M, int N, int K)
{
  __shared__ float Xs[16][132];
  __shared__ float Ws[16][132];
  __shared__ float red[128][17];
  const int tid = threadIdx.x;
  const int tm = tid & 15, tn = tid >> 4;
  const int m0 = blockIdx.y * 128, n0 = blockIdx.x * 128;
  const int cc = tid & 15, r0 = tid >> 4;
  float acc[8][8];
#pragma unroll
  for (int i = 0; i < 8; i++)
#pragma unroll
    for (int j = 0; j < 8; j++) acc[i][j] = 0.f;

  for (int k0 = 0; k0 < K; k0 += 16) {
    const int k = k0 + cc;
    const bool kin = (k < K);
#pragma unroll
    for (int i = 0; i < 8; i++) {
      const int r = r0 + i * 16;
      Xs[cc][r] = kin ? X[(size_t)(m0 + r) * K + k] : 0.f;
      Ws[cc][r] = kin ? W[(size_t)(n0 + r) * K + k] : 0.f;
    }
    __syncthreads();
#pragma unroll
    for (int kk = 0; kk < 16; kk++) {
      float a[8], bv[8];
      *(float4*)&a[0] = *(const float4*)&Xs[kk][tm * 8];
      *(float4*)&a[4] = *(const float4*)&Xs[kk][tm * 8 + 4];
      *(float4*)&bv[0] = *(const float4*)&Ws[kk][tn * 8];
      *(float4*)&bv[4] = *(const float4*)&Ws[kk][tn * 8 + 4];
#pragma unroll
      for (int i = 0; i < 8; i++)
#pragma unroll
        for (int j = 0; j < 8; j++) acc[i][j] += a[i] * bv[j];
    }
    __syncthreads();
  }

  const int col0 = n0 + tn * 8;
  float bb8[8], cc8[8];
#pragma unroll
  for (int j = 0; j < 8; j++) { bb8[j] = mlp_b[col0 + j]; cc8[j] = ctx[col0 + j]; }
#pragma unroll
  for (int i = 0; i < 8; i++) {
    float p = 0.f;
#pragma unroll
    for (int j = 0; j < 8; j++) p += tanhfast(acc[i][j] + bb8[j]) * cc8[j];
    red[tm * 8 + i][tn] = p;
  }
  __syncthreads();
  if (tid < 128) {
    float sum = 0.f;
#pragma unroll
    for (int q = 0; q < 16; q++) sum += red[tid][q];
    atomicAdd(&scores[m0 + tid], sum);
  }
}

// ---------------- LSTM recurrence chunk (both directions) ----------------
// blocks: 256 = d(2) * g(16 batch-groups of 8) * s(8 h-slices of 32)
// thread: tid = hh*8 + kc; owns cell (b = g*8+kc, hdim = s*32+hh)
__global__ __launch_bounds__(256, 1) void lstm_rec(
    const float* __restrict__ xgF, const float* __restrict__ xgR,
    const float* __restrict__ whF, const float* __restrict__ whR,
    const int* __restrict__ lengths, float* __restrict__ hout,
    float* __restrict__ hbuf, float* __restrict__ cbuf,
    int* __restrict__ cnt, int t0)
{
  // ht: h_prev tile [8 batches][256], chunk-padded: addr(bb,k)=bb*288+(k>>5)*36+(k&31)
  __shared__ float ht[2304];
  const int tid = threadIdx.x;
  const int blk = blockIdx.x;
  const int d = blk >> 7;
  const int g = (blk >> 3) & 15;
  const int s = blk & 7;
  const int hh = tid >> 3;
  const int kc = tid & 7;
  const int b = g * 8 + kc;
  const int hdim = s * 32 + hh;
  const float* __restrict__ xg = d ? xgR : xgF;
  const float* __restrict__ wh = d ? whR : whF;

  float wreg[4][32];
#pragma unroll
  for (int gate = 0; gate < 4; gate++) {
    const float* wrow = wh + ((size_t)(gate * 256 + hdim)) * 256 + kc * 32;
#pragma unroll
    for (int j = 0; j < 32; j += 4) {
      float4 v = *(const float4*)(wrow + j);
      wreg[gate][j] = v.x; wreg[gate][j + 1] = v.y;
      wreg[gate][j + 2] = v.z; wreg[gate][j + 3] = v.w;
    }
  }

  float c;
  if (t0 == 0) {
    for (int i = tid; i < 2304; i += 256) ht[i] = 0.f;
    c = 0.f;
  } else {
    // load h(t0-1) tile from hbuf parity slot t0&1, c from cbuf (kernel boundary = sync)
    const int ph0 = t0 & 1;
    const int fi = tid * 8;
    const int b2 = fi >> 8, k2 = fi & 255;
    const float* src = hbuf + ((size_t)(ph0 * 2 + d) * 128 + g * 8 + b2) * 256 + k2;
    float4 v0 = *(const float4*)(src);
    float4 v1 = *(const float4*)(src + 4);
    float* dst = ht + b2 * 288 + ((k2 >> 5) * 36) + (k2 & 31);
    *(float4*)dst = v0;
    *(float4*)(dst + 4) = v1;
    c = cbuf[((size_t)d * 128 + b) * 256 + hdim];
  }
  int lb = lengths[b]; if (lb < 1) lb = 1;
  const int cntbase = d * 16 + g;
  __syncthreads();

  // prefetch first step's input-projection gates
  const float* xr0 = xg + ((size_t)b) * 1024 + hdim;   // chunk-local step 0
  float x0 = xr0[0], x1 = xr0[256], x2 = xr0[512], x3 = xr0[768];

  const int tend = t0 + TC;
  for (int t = t0; t < tend; t++) {
    float part[4][8];
#pragma unroll
    for (int gate = 0; gate < 4; gate++)
#pragma unroll
      for (int bb = 0; bb < 8; bb++) part[gate][bb] = 0.f;

#pragma unroll
    for (int bb = 0; bb < 8; bb++) {
      const float* hrow = ht + bb * 288 + kc * 36;
#pragma unroll
      for (int j = 0; j < 32; j += 4) {
        float4 h4 = *(const float4*)(hrow + j);
#pragma unroll
        for (int gate = 0; gate < 4; gate++) {
          part[gate][bb] += h4.x * wreg[gate][j]     + h4.y * wreg[gate][j + 1]
                          + h4.z * wreg[gate][j + 2] + h4.w * wreg[gate][j + 3];
        }
      }
    }

    // halving butterfly over kc: after 3 rounds lane kc holds full sum for bb==kc
    float n4[4][4];
#pragma unroll
    for (int gate = 0; gate < 4; gate++)
#pragma unroll
      for (int q = 0; q < 4; q++) {
        const float keep = (kc & 4) ? part[gate][q + 4] : part[gate][q];
        const float send = (kc & 4) ? part[gate][q]     : part[gate][q + 4];
        n4[gate][q] = keep + __shfl_xor(send, 4, 8);
      }
    float n2[4][2];
#pragma unroll
    for (int gate = 0; gate < 4; gate++)
#pragma unroll
      for (int q = 0; q < 2; q++) {
        const float keep = (kc & 2) ? n4[gate][q + 2] : n4[gate][q];
        const float send = (kc & 2) ? n4[gate][q]     : n4[gate][q + 2];
        n2[gate][q] = keep + __shfl_xor(send, 2, 8);
      }
    float gsum[4];
#pragma unroll
    for (int gate = 0; gate < 4; gate++) {
      const float keep = (kc & 1) ? n2[gate][1] : n2[gate][0];
      const float send = (kc & 1) ? n2[gate][0] : n2[gate][1];
      gsum[gate] = keep + __shfl_xor(send, 1, 8);
    }

    const float si = sigf(gsum[0] + x0);
    const float sf = sigf(gsum[1] + x1);
    const float tg = tanhfast(gsum[2] + x2);
    const float so = sigf(gsum[3] + x3);
    c = sf * c + si * tg;
    const float h = so * tanhfast(c);

    const int tin = d ? ((t < lb) ? (lb - 1 - t) : t) : t;
    hout[((size_t)tin * 128 + b) * 512 + d * 256 + hdim] = h;

    // publish h: RELAXED agent-scope store (sc0sc1, lands at coherent point, no
    // cache maintenance).
    const int ph = (t + 1) & 1;
    __hip_atomic_store(&hbuf[((size_t)(ph * 2 + d) * 128 + b) * 256 + hdim], h,
                       __ATOMIC_RELAXED, __HIP_MEMORY_SCOPE_AGENT);

    if (t < tend - 1) {
      // prefetch next step's xg now -- latency hides under the sync
      const float* xn = xg + ((size_t)(t + 1 - t0) * 128 + b) * 1024 + hdim;
      const float nx0 = xn[0], nx1 = xn[256], nx2 = xn[512], nx3 = xn[768];

      // barrier drains vmcnt(0): this block's hbuf stores are globally visible
      __syncthreads();
      int* cp = cnt + t * 32 + cntbase;
      if (tid == 0)
        __hip_atomic_fetch_add(cp, 1, __ATOMIC_RELAXED, __HIP_MEMORY_SCOPE_AGENT);
      // all threads poll (same-addr wave loads coalesce). UNSIGNED compare:
      // poisoned/replayed flags (>=8) free-pass instead of spinning.
      int it = 0;
      unsigned v;
      do {
        v = (unsigned)__hip_atomic_load(cp, __ATOMIC_RELAXED, __HIP_MEMORY_SCOPE_AGENT);
      } while (v < 8u && ++it < 30000);
      __asm__ __volatile__("" ::: "memory");

      // gather peers' h (uncached agent-scope loads; data valid once flag==8)
      const int bb = tid >> 5, kbase = tid & 31;
      const float* src = hbuf + ((size_t)(ph * 2 + d) * 128 + g * 8 + bb) * 256;
      float vals[8];
#pragma unroll
      for (int j = 0; j < 8; j++)
        vals[j] = __hip_atomic_load(&src[kbase + 32 * j],
                                    __ATOMIC_RELAXED, __HIP_MEMORY_SCOPE_AGENT);
#pragma unroll
      for (int j = 0; j < 8; j++) ht[bb * 288 + j * 36 + kbase] = vals[j];
      __syncthreads();

      x0 = nx0; x1 = nx1; x2 = nx2; x3 = nx3;
    }
  }
  // persist c for next chunk
  cbuf[((size_t)d * 128 + b) * 256 + hdim] = c;
}

// ---------------- masked softmax over t + weighted sum ----------------
__global__ __launch_bounds__(256) void attn_final(
    const float* __restrict__ h2, const float* __restrict__ scores,
    const int* __restrict__ lengths, float* __restrict__ out)
{
  __shared__ float sl[256];
  __shared__ float red[256];
  const int b = blockIdx.x, tid = threadIdx.x;
  int lb = lengths[b]; if (lb < 1) lb = 1;
  const float sc = scores[(size_t)tid * 128 + b];
  const bool valid = (tid < lb);
  red[tid] = valid ? sc : -1e30f;
  __syncthreads();
  for (int off = 128; off > 0; off >>= 1) {
    if (tid < off) red[tid] = fmaxf(red[tid], red[tid + off]);
    __syncthreads();
  }
  const float mx = red[0];
  __syncthreads();
  const float p = valid ? __expf(sc - mx) : 0.f;
  red[tid] = p;
  __syncthreads();
  for (int off = 128; off > 0; off >>= 1) {
    if (tid < off) red[tid] += red[tid + off];
    __syncthreads();
  }
  const float inv = 1.f / red[0];
  __syncthreads();
  sl[tid] = p * inv;
  __syncthreads();

  float ax = 0.f, ay = 0.f;
  const int dd = tid * 2;
  for (int t = 0; t < 256; t++) {
    const float w = sl[t];
    if (w != 0.f) {  // wave-uniform
      const float* row = h2 + ((size_t)t * 128 + b) * 512 + dd;
      ax += w * row[0];
      ay += w * row[1];
    }
  }
  float2 r; r.x = ax; r.y = ay;
  *(float2*)(out + (size_t)b * 512 + dd) = r;
}

// ---------------- launch ----------------
extern "C" void kernel_launch(void* const* d_in, const int* in_sizes, int n_in,
                              void* d_out, int out_size, void* d_ws, size_t ws_size,
                              hipStream_t stream) {
  (void)in_sizes; (void)n_in; (void)out_size; (void)ws_size;
  const float* x        = (const float*)d_in[0];
  const int*   lengths  = (const int*)d_in[1];
  const float* w_ih_l0  = (const float*)d_in[2];
  const float* w_hh_l0  = (const float*)d_in[3];
  const float* b_ih_l0  = (const float*)d_in[4];
  const float* b_hh_l0  = (const float*)d_in[5];
  const float* w_ih_l0r = (const float*)d_in[6];
  const float* w_hh_l0r = (const float*)d_in[7];
  const float* b_ih_l0r = (const float*)d_in[8];
  const float* b_hh_l0r = (const float*)d_in[9];
  const float* w_ih_l1  = (const float*)d_in[10];
  const float* w_hh_l1  = (const float*)d_in[11];
  const float* b_ih_l1  = (const float*)d_in[12];
  const float* b_hh_l1  = (const float*)d_in[13];
  const float* w_ih_l1r = (const float*)d_in[14];
  const float* w_hh_l1r = (const float*)d_in[15];
  const float* b_ih_l1r = (const float*)d_in[16];
  const float* b_hh_l1r = (const float*)d_in[17];
  const float* mlp_w    = (const float*)d_in[18];
  const float* mlp_b    = (const float*)d_in[19];
  const float* ctx      = (const float*)d_in[20];
  float* out = (float*)d_out;

  // workspace layout (floats): total ~202.6 MB
  float* ws = (float*)d_ws;
  const size_t XGC = (size_t)TC * B_ * G4H;          // 8,388,608
  const size_t H_SZ = (size_t)T_ * B_ * H2;          // 16,777,216
  float* xgA    = ws;
  float* xgB    = xgA + XGC;
  float* h1     = xgB + XGC;
  float* h2     = h1 + H_SZ;
  float* hbuf   = h2 + H_SZ;                          // 131,072
  float* cbuf   = hbuf + 131072;                      // 131,072
  float* scores = cbuf + 131072;                      // 32,768
  int*   flags  = (int*)(scores + 32768);             // 16,384 ints

  hipMemsetAsync(scores, 0, (size_t)(32768 + 16384) * 4, stream);

  dim3 blk(256);
  const dim3 pgrid(G4H / 128, TC);   // (8, 64)

  // layer 0 (K=300), chunked over time
  for (int c = 0; c < T_ / TC; c++) {
    const int t0 = c * TC;
    proj_gemm<<<pgrid, blk, 0, stream>>>(x, w_ih_l0,  b_ih_l0,  b_hh_l0,  xgA, G4H, D_, lengths, 0, t0);
    proj_gemm<<<pgrid, blk, 0, stream>>>(x, w_ih_l0r, b_ih_l0r, b_hh_l0r, xgB, G4H, D_, lengths, 1, t0);
    lstm_rec<<<256, blk, 0, stream>>>(xgA, xgB, w_hh_l0, w_hh_l0r, lengths, h1, hbuf, cbuf, flags, t0);
  }
  // layer 1 (K=512)
  for (int c = 0; c < T_ / TC; c++) {
    const int t0 = c * TC;
    proj_gemm<<<pgrid, blk, 0, stream>>>(h1, w_ih_l1,  b_ih_l1,  b_hh_l1,  xgA, G4H, H2, lengths, 0, t0);
    proj_gemm<<<pgrid, blk, 0, stream>>>(h1, w_ih_l1r, b_ih_l1r, b_hh_l1r, xgB, G4H, H2, lengths, 1, t0);
    lstm_rec<<<256, blk, 0, stream>>>(xgA, xgB, w_hh_l1, w_hh_l1r, lengths, h2, hbuf, cbuf, flags + 8192, t0);
  }
  // attention
  attn_gemm<<<dim3(H2 / 128, (T_ * B_) / 128), blk, 0, stream>>>(h2, mlp_w, mlp_b, ctx, scores, T_ * B_, H2, H2);
  attn_final<<<B_, blk, 0, stream>>>(h2, scores, lengths, out);
}

// Round 5
// 5577.454 us; speedup vs baseline: 5.4936x; 1.3143x over previous
//
#include <hip/hip_runtime.h>

// SentenceEncodingRNN2: 2-layer BiLSTM (T=256,B=128,D=300,H=256) + attention pooling.
// Round 5: sync overhaul in lstm_rec.
//   R4 counters: 12.1us/step, sync ~11us of it. Root causes: (a) per-step flags for
//   all 32 domains packed into 2 cache lines -> LLC line serialization under 1024
//   polling waves; (b) block-wide arrival (2-3 barriers/step); (c) single-buffered
//   LDS ht forcing an extra barrier.
//   Fixes: 128B-padded flag per (step,domain); wave-granular arrival (in-wave
//   s_waitcnt vmcnt(0) + lane0 add, target 32 = 8 blocks x 4 waves); parity
//   double-buffered LDS ht -> ONE __syncthreads per step; explicit fmaf chains.

#define T_ 256
#define B_ 128
#define D_ 300
#define H_ 256
#define G4H 1024   // 4*H
#define H2 512     // 2*H
#define TC 64      // time-chunk length

// ---------------- helpers ----------------
__device__ __forceinline__ float sigf(float x) { return 1.f / (1.f + __expf(-x)); }
__device__ __forceinline__ float tanhfast(float x) { return 2.f / (1.f + __expf(-2.f * x)) - 1.f; }

// ---------------- projection GEMM (chunked, optional reverse gather) ----------------
// C[lm][n] = sum_k X[srow(lm)][k]*W[n][k] + b1[n]+b2[n]
__global__ __launch_bounds__(256) void proj_gemm(
    const float* __restrict__ X, const float* __restrict__ W,
    const float* __restrict__ bias1, const float* __restrict__ bias2,
    float* __restrict__ C, int N, int K,
    const int* __restrict__ lengths, int rev, int t0)
{
  __shared__ float Xs[16][132];
  __shared__ float Ws[16][132];
  const int tid = threadIdx.x;
  const int tm = tid & 15, tn = tid >> 4;
  const int m0 = blockIdx.y * 128, n0 = blockIdx.x * 128;
  const int cc = tid & 15, r0 = tid >> 4;
  const int s_step = t0 + blockIdx.y;

  int srow[8];
#pragma unroll
  for (int i = 0; i < 8; i++) {
    const int r = r0 + i * 16;          // r == batch index b within tile
    int ss = s_step;
    if (rev) {
      int lb = lengths[r]; if (lb < 1) lb = 1;
      ss = (s_step < lb) ? (lb - 1 - s_step) : s_step;
    }
    srow[i] = ss * 128 + r;
  }

  float acc[8][8];
#pragma unroll
  for (int i = 0; i < 8; i++)
#pragma unroll
    for (int j = 0; j < 8; j++) acc[i][j] = 0.f;

  float rx[8], rw[8];
  {
    const int k = cc;
    const bool kin = (k < K);
#pragma unroll
    for (int i = 0; i < 8; i++) {
      const int r = r0 + i * 16;
      rx[i] = kin ? X[(size_t)srow[i] * K + k] : 0.f;
      rw[i] = kin ? W[(size_t)(n0 + r) * K + k] : 0.f;
    }
  }

  for (int k0 = 0; k0 < K; k0 += 16) {
#pragma unroll
    for (int i = 0; i < 8; i++) {
      const int r = r0 + i * 16;
      Xs[cc][r] = rx[i];
      Ws[cc][r] = rw[i];
    }
    __syncthreads();
    if (k0 + 16 < K) {
      const int k = k0 + 16 + cc;
      const bool kin = (k < K);
#pragma unroll
      for (int i = 0; i < 8; i++) {
        const int r = r0 + i * 16;
        rx[i] = kin ? X[(size_t)srow[i] * K + k] : 0.f;
        rw[i] = kin ? W[(size_t)(n0 + r) * K + k] : 0.f;
      }
    }
#pragma unroll
    for (int kk = 0; kk < 16; kk++) {
      float a[8], bv[8];
      *(float4*)&a[0] = *(const float4*)&Xs[kk][tm * 8];
      *(float4*)&a[4] = *(const float4*)&Xs[kk][tm * 8 + 4];
      *(float4*)&bv[0] = *(const float4*)&Ws[kk][tn * 8];
      *(float4*)&bv[4] = *(const float4*)&Ws[kk][tn * 8 + 4];
#pragma unroll
      for (int i = 0; i < 8; i++)
#pragma unroll
        for (int j = 0; j < 8; j++) acc[i][j] = fmaf(a[i], bv[j], acc[i][j]);
    }
    __syncthreads();
  }

  const int col0 = n0 + tn * 8;
  float bsum[8];
#pragma unroll
  for (int j = 0; j < 8; j++) bsum[j] = bias1[col0 + j] + bias2[col0 + j];
#pragma unroll
  for (int i = 0; i < 8; i++) {
    float* Crow = C + (size_t)(m0 + tm * 8 + i) * N + col0;
    float4 v0, v1;
    v0.x = acc[i][0] + bsum[0]; v0.y = acc[i][1] + bsum[1];
    v0.z = acc[i][2] + bsum[2]; v0.w = acc[i][3] + bsum[3];
    v1.x = acc[i][4] + bsum[4]; v1.y = acc[i][5] + bsum[5];
    v1.z = acc[i][6] + bsum[6]; v1.w = acc[i][7] + bsum[7];
    *(float4*)(Crow) = v0;
    *(float4*)(Crow + 4) = v1;
  }
}

// ---------------- attention score GEMM with fused tanh*ctx epilogue ----------------
__global__ __launch_bounds__(256) void attn_gemm(
    const float* __restrict__ X, const float* __restrict__ W,
    const float* __restrict__ mlp_b, const float* __restrict__ ctx,
    float* __restrict__ scores, int M, int N, int K)
{
  __shared__ float Xs[16][132];
  __shared__ float Ws[16][132];
  __shared__ float red[128][17];
  const int tid = threadIdx.x;
  const int tm = tid & 15, tn = tid >> 4;
  const int m0 = blockIdx.y * 128, n0 = blockIdx.x * 128;
  const int cc = tid & 15, r0 = tid >> 4;
  float acc[8][8];
#pragma unroll
  for (int i = 0; i < 8; i++)
#pragma unroll
    for (int j = 0; j < 8; j++) acc[i][j] = 0.f;

  for (int k0 = 0; k0 < K; k0 += 16) {
    const int k = k0 + cc;
    const bool kin = (k < K);
#pragma unroll
    for (int i = 0; i < 8; i++) {
      const int r = r0 + i * 16;
      Xs[cc][r] = kin ? X[(size_t)(m0 + r) * K + k] : 0.f;
      Ws[cc][r] = kin ? W[(size_t)(n0 + r) * K + k] : 0.f;
    }
    __syncthreads();
#pragma unroll
    for (int kk = 0; kk < 16; kk++) {
      float a[8], bv[8];
      *(float4*)&a[0] = *(const float4*)&Xs[kk][tm * 8];
      *(float4*)&a[4] = *(const float4*)&Xs[kk][tm * 8 + 4];
      *(float4*)&bv[0] = *(const float4*)&Ws[kk][tn * 8];
      *(float4*)&bv[4] = *(const float4*)&Ws[kk][tn * 8 + 4];
#pragma unroll
      for (int i = 0; i < 8; i++)
#pragma unroll
        for (int j = 0; j < 8; j++) acc[i][j] = fmaf(a[i], bv[j], acc[i][j]);
    }
    __syncthreads();
  }

  const int col0 = n0 + tn * 8;
  float bb8[8], cc8[8];
#pragma unroll
  for (int j = 0; j < 8; j++) { bb8[j] = mlp_b[col0 + j]; cc8[j] = ctx[col0 + j]; }
#pragma unroll
  for (int i = 0; i < 8; i++) {
    float p = 0.f;
#pragma unroll
    for (int j = 0; j < 8; j++) p += tanhfast(acc[i][j] + bb8[j]) * cc8[j];
    red[tm * 8 + i][tn] = p;
  }
  __syncthreads();
  if (tid < 128) {
    float sum = 0.f;
#pragma unroll
    for (int q = 0; q < 16; q++) sum += red[tid][q];
    atomicAdd(&scores[m0 + tid], sum);
  }
}

// ---------------- LSTM recurrence chunk (both directions) ----------------
// blocks: 256 = d(2) * g(16 batch-groups of 8) * s(8 h-slices of 32)
// thread: tid = hh*8 + kc; owns cell (b = g*8+kc, hdim = s*32+hh)
// sync: wave-granular arrival on 128B-padded per-(step,domain) flag; target 32.
__global__ __launch_bounds__(256, 1) void lstm_rec(
    const float* __restrict__ xgF, const float* __restrict__ xgR,
    const float* __restrict__ whF, const float* __restrict__ whR,
    const int* __restrict__ lengths, float* __restrict__ hout,
    float* __restrict__ hbuf, float* __restrict__ cbuf,
    int* __restrict__ cnt, int t0)
{
  // ht: parity double-buffered h_prev tile [8 batches][256],
  // addr(bb,k) = bb*288 + (k>>5)*36 + (k&31)
  __shared__ float ht[2][2304];
  const int tid = threadIdx.x;
  const int blk = blockIdx.x;
  const int d = blk >> 7;
  const int g = (blk >> 3) & 15;
  const int s = blk & 7;
  const int hh = tid >> 3;
  const int kc = tid & 7;
  const int b = g * 8 + kc;
  const int hdim = s * 32 + hh;
  const float* __restrict__ xg = d ? xgR : xgF;
  const float* __restrict__ wh = d ? whR : whF;

  float wreg[4][32];
#pragma unroll
  for (int gate = 0; gate < 4; gate++) {
    const float* wrow = wh + ((size_t)(gate * 256 + hdim)) * 256 + kc * 32;
#pragma unroll
    for (int j = 0; j < 32; j += 4) {
      float4 v = *(const float4*)(wrow + j);
      wreg[gate][j] = v.x; wreg[gate][j + 1] = v.y;
      wreg[gate][j + 2] = v.z; wreg[gate][j + 3] = v.w;
    }
  }

  float c;
  float* ht0 = ht[t0 & 1];
  if (t0 == 0) {
    for (int i = tid; i < 2304; i += 256) ht0[i] = 0.f;
    c = 0.f;
  } else {
    // kernel-start acquire makes prior chunk's hbuf/cbuf visible; plain loads ok.
    const int ph0 = t0 & 1;
    const int fi = tid * 8;
    const int b2 = fi >> 8, k2 = fi & 255;
    const float* src = hbuf + ((size_t)(ph0 * 2 + d) * 128 + g * 8 + b2) * 256 + k2;
    float4 v0 = *(const float4*)(src);
    float4 v1 = *(const float4*)(src + 4);
    float* dst = ht0 + b2 * 288 + ((k2 >> 5) * 36) + (k2 & 31);
    *(float4*)dst = v0;
    *(float4*)(dst + 4) = v1;
    c = cbuf[((size_t)d * 128 + b) * 256 + hdim];
  }
  int lb = lengths[b]; if (lb < 1) lb = 1;
  const int cntbase = d * 16 + g;
  __syncthreads();

  // prefetch first step's input-projection gates
  const float* xr0 = xg + ((size_t)b) * 1024 + hdim;   // chunk-local step 0
  float x0 = xr0[0], x1 = xr0[256], x2 = xr0[512], x3 = xr0[768];

  const int tend = t0 + TC;
  for (int t = t0; t < tend; t++) {
    const float* htr = ht[t & 1];
    float part[4][8];
#pragma unroll
    for (int gate = 0; gate < 4; gate++)
#pragma unroll
      for (int bb = 0; bb < 8; bb++) part[gate][bb] = 0.f;

#pragma unroll
    for (int bb = 0; bb < 8; bb++) {
      const float* hrow = htr + bb * 288 + kc * 36;
#pragma unroll
      for (int j = 0; j < 32; j += 4) {
        float4 h4 = *(const float4*)(hrow + j);
#pragma unroll
        for (int gate = 0; gate < 4; gate++) {
          float p = part[gate][bb];
          p = fmaf(h4.x, wreg[gate][j],     p);
          p = fmaf(h4.y, wreg[gate][j + 1], p);
          p = fmaf(h4.z, wreg[gate][j + 2], p);
          p = fmaf(h4.w, wreg[gate][j + 3], p);
          part[gate][bb] = p;
        }
      }
    }

    // halving butterfly over kc: after 3 rounds lane kc holds full sum for bb==kc
    float n4[4][4];
#pragma unroll
    for (int gate = 0; gate < 4; gate++)
#pragma unroll
      for (int q = 0; q < 4; q++) {
        const float keep = (kc & 4) ? part[gate][q + 4] : part[gate][q];
        const float send = (kc & 4) ? part[gate][q]     : part[gate][q + 4];
        n4[gate][q] = keep + __shfl_xor(send, 4, 8);
      }
    float n2[4][2];
#pragma unroll
    for (int gate = 0; gate < 4; gate++)
#pragma unroll
      for (int q = 0; q < 2; q++) {
        const float keep = (kc & 2) ? n4[gate][q + 2] : n4[gate][q];
        const float send = (kc & 2) ? n4[gate][q]     : n4[gate][q + 2];
        n2[gate][q] = keep + __shfl_xor(send, 2, 8);
      }
    float gsum[4];
#pragma unroll
    for (int gate = 0; gate < 4; gate++) {
      const float keep = (kc & 1) ? n2[gate][1] : n2[gate][0];
      const float send = (kc & 1) ? n2[gate][0] : n2[gate][1];
      gsum[gate] = keep + __shfl_xor(send, 1, 8);
    }

    const float si = sigf(gsum[0] + x0);
    const float sf = sigf(gsum[1] + x1);
    const float tg = tanhfast(gsum[2] + x2);
    const float so = sigf(gsum[3] + x3);
    c = sf * c + si * tg;
    const float h = so * tanhfast(c);

    // publish h first (uncached, lands at coherent point), then cached hout store
    const int ph = (t + 1) & 1;
    __hip_atomic_store(&hbuf[((size_t)(ph * 2 + d) * 128 + b) * 256 + hdim], h,
                       __ATOMIC_RELAXED, __HIP_MEMORY_SCOPE_AGENT);
    const int tin = d ? ((t < lb) ? (lb - 1 - t) : t) : t;
    hout[((size_t)tin * 128 + b) * 512 + d * 256 + hdim] = h;

    if (t < tend - 1) {
      // prefetch next step's xg (drains with the same waitcnt, L2-fast)
      const float* xn = xg + ((size_t)(t + 1 - t0) * 128 + b) * 1024 + hdim;
      const float nx0 = xn[0], nx1 = xn[256], nx2 = xn[512], nx3 = xn[768];

      // wave-granular arrival: drain this wave's stores, lane 0 signals.
      __asm__ __volatile__("s_waitcnt vmcnt(0) lgkmcnt(0)" ::: "memory");
      int* cp = cnt + ((size_t)t * 32 + cntbase) * 32;   // 128B-padded flag line
      if ((tid & 63) == 0)
        __hip_atomic_fetch_add(cp, 1, __ATOMIC_RELAXED, __HIP_MEMORY_SCOPE_AGENT);
      // all lanes poll (coalesces to 1 req/wave). UNSIGNED: poisoned flags free-pass.
      int it = 0;
      unsigned v;
      do {
        v = (unsigned)__hip_atomic_load(cp, __ATOMIC_RELAXED, __HIP_MEMORY_SCOPE_AGENT);
      } while (v < 32u && ++it < 30000);
      __asm__ __volatile__("" ::: "memory");

      // gather peers' h into parity buffer (uncached loads, valid once flag==32)
      const int bb = tid >> 5, kbase = tid & 31;
      const float* src = hbuf + ((size_t)(ph * 2 + d) * 128 + g * 8 + bb) * 256;
      float vals[8];
#pragma unroll
      for (int j = 0; j < 8; j++)
        vals[j] = __hip_atomic_load(&src[kbase + 32 * j],
                                    __ATOMIC_RELAXED, __HIP_MEMORY_SCOPE_AGENT);
      float* htw = ht[ph];
#pragma unroll
      for (int j = 0; j < 8; j++) htw[bb * 288 + j * 36 + kbase] = vals[j];

      x0 = nx0; x1 = nx1; x2 = nx2; x3 = nx3;
      __syncthreads();   // the ONE barrier: parity writes visible to all waves
    }
  }
  // persist c for next chunk (end-of-kernel release writes back)
  cbuf[((size_t)d * 128 + b) * 256 + hdim] = c;
}

// ---------------- masked softmax over t + weighted sum ----------------
__global__ __launch_bounds__(256) void attn_final(
    const float* __restrict__ h2, const float* __restrict__ scores,
    const int* __restrict__ lengths, float* __restrict__ out)
{
  __shared__ float sl[256];
  __shared__ float red[256];
  const int b = blockIdx.x, tid = threadIdx.x;
  int lb = lengths[b]; if (lb < 1) lb = 1;
  const float sc = scores[(size_t)tid * 128 + b];
  const bool valid = (tid < lb);
  red[tid] = valid ? sc : -1e30f;
  __syncthreads();
  for (int off = 128; off > 0; off >>= 1) {
    if (tid < off) red[tid] = fmaxf(red[tid], red[tid + off]);
    __syncthreads();
  }
  const float mx = red[0];
  __syncthreads();
  const float p = valid ? __expf(sc - mx) : 0.f;
  red[tid] = p;
  __syncthreads();
  for (int off = 128; off > 0; off >>= 1) {
    if (tid < off) red[tid] += red[tid + off];
    __syncthreads();
  }
  const float inv = 1.f / red[0];
  __syncthreads();
  sl[tid] = p * inv;
  __syncthreads();

  float ax = 0.f, ay = 0.f;
  const int dd = tid * 2;
  for (int t = 0; t < 256; t++) {
    const float w = sl[t];
    if (w != 0.f) {  // wave-uniform
      const float* row = h2 + ((size_t)t * 128 + b) * 512 + dd;
      ax += w * row[0];
      ay += w * row[1];
    }
  }
  float2 r; r.x = ax; r.y = ay;
  *(float2*)(out + (size_t)b * 512 + dd) = r;
}

// ---------------- launch ----------------
extern "C" void kernel_launch(void* const* d_in, const int* in_sizes, int n_in,
                              void* d_out, int out_size, void* d_ws, size_t ws_size,
                              hipStream_t stream) {
  (void)in_sizes; (void)n_in; (void)out_size; (void)ws_size;
  const float* x        = (const float*)d_in[0];
  const int*   lengths  = (const int*)d_in[1];
  const float* w_ih_l0  = (const float*)d_in[2];
  const float* w_hh_l0  = (const float*)d_in[3];
  const float* b_ih_l0  = (const float*)d_in[4];
  const float* b_hh_l0  = (const float*)d_in[5];
  const float* w_ih_l0r = (const float*)d_in[6];
  const float* w_hh_l0r = (const float*)d_in[7];
  const float* b_ih_l0r = (const float*)d_in[8];
  const float* b_hh_l0r = (const float*)d_in[9];
  const float* w_ih_l1  = (const float*)d_in[10];
  const float* w_hh_l1  = (const float*)d_in[11];
  const float* b_ih_l1  = (const float*)d_in[12];
  const float* b_hh_l1  = (const float*)d_in[13];
  const float* w_ih_l1r = (const float*)d_in[14];
  const float* w_hh_l1r = (const float*)d_in[15];
  const float* b_ih_l1r = (const float*)d_in[16];
  const float* b_hh_l1r = (const float*)d_in[17];
  const float* mlp_w    = (const float*)d_in[18];
  const float* mlp_b    = (const float*)d_in[19];
  const float* ctx      = (const float*)d_in[20];
  float* out = (float*)d_out;

  // workspace layout (floats): ~205 MB
  float* ws = (float*)d_ws;
  const size_t XGC  = (size_t)TC * B_ * G4H;          // 8,388,608
  const size_t H_SZ = (size_t)T_ * B_ * H2;           // 16,777,216
  const size_t FLAGS_PER_LAYER = (size_t)T_ * 32 * 32; // 262,144 ints (128B/line)
  float* xgA    = ws;
  float* xgB    = xgA + XGC;
  float* h1     = xgB + XGC;
  float* h2     = h1 + H_SZ;
  float* hbuf   = h2 + H_SZ;                          // 131,072
  float* cbuf   = hbuf + 131072;                      // 131,072
  float* scores = cbuf + 131072;                      // 32,768
  int*   flags  = (int*)(scores + 32768);             // 2 * 262,144 ints

  // zero scores + both layers' flags (contiguous): (32768 + 524288)*4 bytes
  hipMemsetAsync(scores, 0, (size_t)(32768 + 2 * FLAGS_PER_LAYER) * 4, stream);

  dim3 blk(256);
  const dim3 pgrid(G4H / 128, TC);   // (8, 64)

  // layer 0 (K=300), chunked over time
  for (int c = 0; c < T_ / TC; c++) {
    const int t0 = c * TC;
    proj_gemm<<<pgrid, blk, 0, stream>>>(x, w_ih_l0,  b_ih_l0,  b_hh_l0,  xgA, G4H, D_, lengths, 0, t0);
    proj_gemm<<<pgrid, blk, 0, stream>>>(x, w_ih_l0r, b_ih_l0r, b_hh_l0r, xgB, G4H, D_, lengths, 1, t0);
    lstm_rec<<<256, blk, 0, stream>>>(xgA, xgB, w_hh_l0, w_hh_l0r, lengths, h1, hbuf, cbuf, flags, t0);
  }
  // layer 1 (K=512)
  for (int c = 0; c < T_ / TC; c++) {
    const int t0 = c * TC;
    proj_gemm<<<pgrid, blk, 0, stream>>>(h1, w_ih_l1,  b_ih_l1,  b_hh_l1,  xgA, G4H, H2, lengths, 0, t0);
    proj_gemm<<<pgrid, blk, 0, stream>>>(h1, w_ih_l1r, b_ih_l1r, b_hh_l1r, xgB, G4H, H2, lengths, 1, t0);
    lstm_rec<<<256, blk, 0, stream>>>(xgA, xgB, w_hh_l1, w_hh_l1r, lengths, h2, hbuf, cbuf,
                                      flags + FLAGS_PER_LAYER, t0);
  }
  // attention
  attn_gemm<<<dim3(H2 / 128, (T_ * B_) / 128), blk, 0, stream>>>(h2, mlp_w, mlp_b, ctx, scores, T_ * B_, H2, H2);
  attn_final<<<B_, blk, 0, stream>>>(h2, scores, lengths, out);
}

// Round 6
// 5182.042 us; speedup vs baseline: 5.9128x; 1.0763x over previous
//
#include <hip/hip_runtime.h>

// SentenceEncodingRNN2: 2-layer BiLSTM (T=256,B=128,D=300,H=256) + attention pooling.
// Round 6: fused tag+data poll in lstm_rec (removes the separate gather LLC round
//          and the flag RMW), dual-direction proj_gemm (halve proj launches).
//   R5 counters: 7.3us/step = 2.0 VALU + 0.5 LDS + ~4.5 sync. Sync chain had TWO
//   sequential LLC rounds after flag-observe (poll, then gather). New protocol:
//   producer wave stores h -> s_waitcnt vmcnt(0) -> lane0 stores tag(t+1) into a
//   launch-zeroed per-(t,d,g,s,wave) slot; consumer polls 8 tags + 8 data values in
//   ONE burst and accepts when tags match. Producer-side 0.9us ACK margin between
//   data and tag stores covers same-burst load skew.

#define T_ 256
#define B_ 128
#define D_ 300
#define H_ 256
#define G4H 1024   // 4*H
#define H2 512     // 2*H
#define TC 64      // time-chunk length
#define TAGS_PER_LAYER (256 * 2 * 16 * 8 * 4)   // [t][d][g][s][w] = 262144 ints

// ---------------- helpers ----------------
__device__ __forceinline__ float sigf(float x) { return 1.f / (1.f + __expf(-x)); }
__device__ __forceinline__ float tanhfast(float x) { return 2.f / (1.f + __expf(-2.f * x)) - 1.f; }

// ---------------- dual-direction projection GEMM (chunked, reverse gather) -------
// z=0: C0[lm][n] = X[s*128+b] @ W0^T + bf ; z=1: C1 = X[revidx(s)*128+b] @ W1^T + br
__global__ __launch_bounds__(256) void proj_gemm2(
    const float* __restrict__ X,
    const float* __restrict__ W0, const float* __restrict__ W1,
    const float* __restrict__ b1f, const float* __restrict__ b2f,
    const float* __restrict__ b1r, const float* __restrict__ b2r,
    float* __restrict__ C0, float* __restrict__ C1,
    int N, int K, const int* __restrict__ lengths, int t0)
{
  __shared__ float Xs[16][132];
  __shared__ float Ws[16][132];
  const int rev = blockIdx.z;
  const float* __restrict__ W = rev ? W1 : W0;
  const float* __restrict__ bias1 = rev ? b1r : b1f;
  const float* __restrict__ bias2 = rev ? b2r : b2f;
  float* __restrict__ C = rev ? C1 : C0;

  const int tid = threadIdx.x;
  const int tm = tid & 15, tn = tid >> 4;
  const int m0 = blockIdx.y * 128, n0 = blockIdx.x * 128;
  const int cc = tid & 15, r0 = tid >> 4;
  const int s_step = t0 + blockIdx.y;

  int srow[8];
#pragma unroll
  for (int i = 0; i < 8; i++) {
    const int r = r0 + i * 16;          // r == batch index b within tile
    int ss = s_step;
    if (rev) {
      int lb = lengths[r]; if (lb < 1) lb = 1;
      ss = (s_step < lb) ? (lb - 1 - s_step) : s_step;
    }
    srow[i] = ss * 128 + r;
  }

  float acc[8][8];
#pragma unroll
  for (int i = 0; i < 8; i++)
#pragma unroll
    for (int j = 0; j < 8; j++) acc[i][j] = 0.f;

  float rx[8], rw[8];
  {
    const int k = cc;
    const bool kin = (k < K);
#pragma unroll
    for (int i = 0; i < 8; i++) {
      const int r = r0 + i * 16;
      rx[i] = kin ? X[(size_t)srow[i] * K + k] : 0.f;
      rw[i] = kin ? W[(size_t)(n0 + r) * K + k] : 0.f;
    }
  }

  for (int k0 = 0; k0 < K; k0 += 16) {
#pragma unroll
    for (int i = 0; i < 8; i++) {
      const int r = r0 + i * 16;
      Xs[cc][r] = rx[i];
      Ws[cc][r] = rw[i];
    }
    __syncthreads();
    if (k0 + 16 < K) {
      const int k = k0 + 16 + cc;
      const bool kin = (k < K);
#pragma unroll
      for (int i = 0; i < 8; i++) {
        const int r = r0 + i * 16;
        rx[i] = kin ? X[(size_t)srow[i] * K + k] : 0.f;
        rw[i] = kin ? W[(size_t)(n0 + r) * K + k] : 0.f;
      }
    }
#pragma unroll
    for (int kk = 0; kk < 16; kk++) {
      float a[8], bv[8];
      *(float4*)&a[0] = *(const float4*)&Xs[kk][tm * 8];
      *(float4*)&a[4] = *(const float4*)&Xs[kk][tm * 8 + 4];
      *(float4*)&bv[0] = *(const float4*)&Ws[kk][tn * 8];
      *(float4*)&bv[4] = *(const float4*)&Ws[kk][tn * 8 + 4];
#pragma unroll
      for (int i = 0; i < 8; i++)
#pragma unroll
        for (int j = 0; j < 8; j++) acc[i][j] = fmaf(a[i], bv[j], acc[i][j]);
    }
    __syncthreads();
  }

  const int col0 = n0 + tn * 8;
  float bsum[8];
#pragma unroll
  for (int j = 0; j < 8; j++) bsum[j] = bias1[col0 + j] + bias2[col0 + j];
#pragma unroll
  for (int i = 0; i < 8; i++) {
    float* Crow = C + (size_t)(m0 + tm * 8 + i) * N + col0;
    float4 v0, v1;
    v0.x = acc[i][0] + bsum[0]; v0.y = acc[i][1] + bsum[1];
    v0.z = acc[i][2] + bsum[2]; v0.w = acc[i][3] + bsum[3];
    v1.x = acc[i][4] + bsum[4]; v1.y = acc[i][5] + bsum[5];
    v1.z = acc[i][6] + bsum[6]; v1.w = acc[i][7] + bsum[7];
    *(float4*)(Crow) = v0;
    *(float4*)(Crow + 4) = v1;
  }
}

// ---------------- attention score GEMM with fused tanh*ctx epilogue ----------------
__global__ __launch_bounds__(256) void attn_gemm(
    const float* __restrict__ X, const float* __restrict__ W,
    const float* __restrict__ mlp_b, const float* __restrict__ ctx,
    float* __restrict__ scores, int M, int N, int K)
{
  __shared__ float Xs[16][132];
  __shared__ float Ws[16][132];
  __shared__ float red[128][17];
  const int tid = threadIdx.x;
  const int tm = tid & 15, tn = tid >> 4;
  const int m0 = blockIdx.y * 128, n0 = blockIdx.x * 128;
  const int cc = tid & 15, r0 = tid >> 4;
  float acc[8][8];
#pragma unroll
  for (int i = 0; i < 8; i++)
#pragma unroll
    for (int j = 0; j < 8; j++) acc[i][j] = 0.f;

  for (int k0 = 0; k0 < K; k0 += 16) {
    const int k = k0 + cc;
    const bool kin = (k < K);
#pragma unroll
    for (int i = 0; i < 8; i++) {
      const int r = r0 + i * 16;
      Xs[cc][r] = kin ? X[(size_t)(m0 + r) * K + k] : 0.f;
      Ws[cc][r] = kin ? W[(size_t)(n0 + r) * K + k] : 0.f;
    }
    __syncthreads();
#pragma unroll
    for (int kk = 0; kk < 16; kk++) {
      float a[8], bv[8];
      *(float4*)&a[0] = *(const float4*)&Xs[kk][tm * 8];
      *(float4*)&a[4] = *(const float4*)&Xs[kk][tm * 8 + 4];
      *(float4*)&bv[0] = *(const float4*)&Ws[kk][tn * 8];
      *(float4*)&bv[4] = *(const float4*)&Ws[kk][tn * 8 + 4];
#pragma unroll
      for (int i = 0; i < 8; i++)
#pragma unroll
        for (int j = 0; j < 8; j++) acc[i][j] = fmaf(a[i], bv[j], acc[i][j]);
    }
    __syncthreads();
  }

  const int col0 = n0 + tn * 8;
  float bb8[8], cc8[8];
#pragma unroll
  for (int j = 0; j < 8; j++) { bb8[j] = mlp_b[col0 + j]; cc8[j] = ctx[col0 + j]; }
#pragma unroll
  for (int i = 0; i < 8; i++) {
    float p = 0.f;
#pragma unroll
    for (int j = 0; j < 8; j++) p += tanhfast(acc[i][j] + bb8[j]) * cc8[j];
    red[tm * 8 + i][tn] = p;
  }
  __syncthreads();
  if (tid < 128) {
    float sum = 0.f;
#pragma unroll
    for (int q = 0; q < 16; q++) sum += red[tid][q];
    atomicAdd(&scores[m0 + tid], sum);
  }
}

// ---------------- LSTM recurrence chunk (both directions) ----------------
// blocks: 256 = d(2) * g(16 batch-groups of 8) * s(8 h-slices of 32)
// thread: tid = hh*8 + kc; owns cell (b = g*8+kc, hdim = s*32+hh)
// sync: producer wave stores h -> waitcnt -> lane0 stores tag(t+1); consumer polls
//       8 tags + 8 data in one burst (single LLC round after tag visible).
__global__ __launch_bounds__(256, 1) void lstm_rec(
    const float* __restrict__ xgF, const float* __restrict__ xgR,
    const float* __restrict__ whF, const float* __restrict__ whR,
    const int* __restrict__ lengths, float* __restrict__ hout,
    float* __restrict__ hbuf, float* __restrict__ cbuf,
    int* __restrict__ tags, int t0)
{
  // ht: parity double-buffered h_prev tile [8 batches][256],
  // addr(bb,k) = bb*288 + (k>>5)*36 + (k&31)
  __shared__ float ht[2][2304];
  const int tid = threadIdx.x;
  const int blk = blockIdx.x;
  const int d = blk >> 7;
  const int g = (blk >> 3) & 15;
  const int s = blk & 7;
  const int hh = tid >> 3;
  const int kc = tid & 7;
  const int b = g * 8 + kc;
  const int hdim = s * 32 + hh;
  const float* __restrict__ xg = d ? xgR : xgF;
  const float* __restrict__ wh = d ? whR : whF;

  float wreg[4][32];
#pragma unroll
  for (int gate = 0; gate < 4; gate++) {
    const float* wrow = wh + ((size_t)(gate * 256 + hdim)) * 256 + kc * 32;
#pragma unroll
    for (int j = 0; j < 32; j += 4) {
      float4 v = *(const float4*)(wrow + j);
      wreg[gate][j] = v.x; wreg[gate][j + 1] = v.y;
      wreg[gate][j + 2] = v.z; wreg[gate][j + 3] = v.w;
    }
  }

  float c;
  float* ht0 = ht[t0 & 1];
  if (t0 == 0) {
    for (int i = tid; i < 2304; i += 256) ht0[i] = 0.f;
    c = 0.f;
  } else {
    // kernel-boundary sync makes prior chunk's hbuf/cbuf visible; plain loads ok.
    const int ph0 = t0 & 1;
    const int fi = tid * 8;
    const int b2 = fi >> 8, k2 = fi & 255;
    const float* src = hbuf + ((size_t)(ph0 * 2 + d) * 128 + g * 8 + b2) * 256 + k2;
    float4 v0 = *(const float4*)(src);
    float4 v1 = *(const float4*)(src + 4);
    float* dst = ht0 + b2 * 288 + ((k2 >> 5) * 36) + (k2 & 31);
    *(float4*)dst = v0;
    *(float4*)(dst + 4) = v1;
    c = cbuf[((size_t)d * 128 + b) * 256 + hdim];
  }
  int lb = lengths[b]; if (lb < 1) lb = 1;
  __syncthreads();

  // prefetch first step's input-projection gates
  const float* xr0 = xg + ((size_t)b) * 1024 + hdim;   // chunk-local step 0
  float x0 = xr0[0], x1 = xr0[256], x2 = xr0[512], x3 = xr0[768];

  const int wave = tid >> 6;
  const int bb = tid >> 5, kbase = tid & 31;   // consumer: batch-in-group, hh-in-slice
  const int wsrc = kbase >> 3;                  // producer wave that wrote offset kbase

  const int tend = t0 + TC;
  for (int t = t0; t < tend; t++) {
    const float* htr = ht[t & 1];
    float part[4][8];
#pragma unroll
    for (int gate = 0; gate < 4; gate++)
#pragma unroll
      for (int q = 0; q < 8; q++) part[gate][q] = 0.f;

#pragma unroll
    for (int q = 0; q < 8; q++) {
      const float* hrow = htr + q * 288 + kc * 36;
#pragma unroll
      for (int j = 0; j < 32; j += 4) {
        float4 h4 = *(const float4*)(hrow + j);
#pragma unroll
        for (int gate = 0; gate < 4; gate++) {
          float p = part[gate][q];
          p = fmaf(h4.x, wreg[gate][j],     p);
          p = fmaf(h4.y, wreg[gate][j + 1], p);
          p = fmaf(h4.z, wreg[gate][j + 2], p);
          p = fmaf(h4.w, wreg[gate][j + 3], p);
          part[gate][q] = p;
        }
      }
    }

    // halving butterfly over kc: after 3 rounds lane kc holds full sum for q==kc
    float n4[4][4];
#pragma unroll
    for (int gate = 0; gate < 4; gate++)
#pragma unroll
      for (int q = 0; q < 4; q++) {
        const float keep = (kc & 4) ? part[gate][q + 4] : part[gate][q];
        const float send = (kc & 4) ? part[gate][q]     : part[gate][q + 4];
        n4[gate][q] = keep + __shfl_xor(send, 4, 8);
      }
    float n2[4][2];
#pragma unroll
    for (int gate = 0; gate < 4; gate++)
#pragma unroll
      for (int q = 0; q < 2; q++) {
        const float keep = (kc & 2) ? n4[gate][q + 2] : n4[gate][q];
        const float send = (kc & 2) ? n4[gate][q]     : n4[gate][q + 2];
        n2[gate][q] = keep + __shfl_xor(send, 2, 8);
      }
    float gsum[4];
#pragma unroll
    for (int gate = 0; gate < 4; gate++) {
      const float keep = (kc & 1) ? n2[gate][1] : n2[gate][0];
      const float send = (kc & 1) ? n2[gate][0] : n2[gate][1];
      gsum[gate] = keep + __shfl_xor(send, 1, 8);
    }

    const float si = sigf(gsum[0] + x0);
    const float sf = sigf(gsum[1] + x1);
    const float tg = tanhfast(gsum[2] + x2);
    const float so = sigf(gsum[3] + x3);
    c = sf * c + si * tg;
    const float h = so * tanhfast(c);

    // publish h (uncached, lands at coherent point), then cached hout store
    const int ph = (t + 1) & 1;
    __hip_atomic_store(&hbuf[((size_t)(ph * 2 + d) * 128 + b) * 256 + hdim], h,
                       __ATOMIC_RELAXED, __HIP_MEMORY_SCOPE_AGENT);
    const int tin = d ? ((t < lb) ? (lb - 1 - t) : t) : t;
    hout[((size_t)tin * 128 + b) * 512 + d * 256 + hdim] = h;

    if (t < tend - 1) {
      // prefetch next step's xg (drains with the same waitcnt, L2-fast)
      const float* xn = xg + ((size_t)(t + 1 - t0) * 128 + b) * 1024 + hdim;
      const float nx0 = xn[0], nx1 = xn[256], nx2 = xn[512], nx3 = xn[768];

      // producer side: drain this wave's stores, lane0 signals its tag
      __asm__ __volatile__("s_waitcnt vmcnt(0) lgkmcnt(0)" ::: "memory");
      int* tagbase = tags + (((size_t)t * 2 + d) * 16 + g) * 32;   // [s][w]
      if ((tid & 63) == 0)
        __hip_atomic_store(&tagbase[s * 4 + wave], t + 1,
                           __ATOMIC_RELAXED, __HIP_MEMORY_SCOPE_AGENT);

      // consumer side: fused poll -- 8 tags + 8 data values per thread, one burst
      const float* src = hbuf + ((size_t)(ph * 2 + d) * 128 + g * 8 + bb) * 256 + kbase;
      float vals[8];
      int it = 0;
      for (;;) {
        int tg8[8];
#pragma unroll
        for (int j = 0; j < 8; j++)
          tg8[j] = __hip_atomic_load(&tagbase[j * 4 + wsrc],
                                     __ATOMIC_RELAXED, __HIP_MEMORY_SCOPE_AGENT);
#pragma unroll
        for (int j = 0; j < 8; j++)
          vals[j] = __hip_atomic_load(&src[32 * j],
                                      __ATOMIC_RELAXED, __HIP_MEMORY_SCOPE_AGENT);
        bool ok = true;
#pragma unroll
        for (int j = 0; j < 8; j++) ok &= (tg8[j] == t + 1);
        if (ok || ++it >= 20000) break;
      }

      float* htw = ht[ph];
#pragma unroll
      for (int j = 0; j < 8; j++) htw[bb * 288 + j * 36 + kbase] = vals[j];

      x0 = nx0; x1 = nx1; x2 = nx2; x3 = nx3;
      __syncthreads();   // the ONE barrier per step
    }
  }
  // persist c for next chunk (end-of-kernel release writes back)
  cbuf[((size_t)d * 128 + b) * 256 + hdim] = c;
}

// ---------------- masked softmax over t + weighted sum ----------------
__global__ __launch_bounds__(256) void attn_final(
    const float* __restrict__ h2, const float* __restrict__ scores,
    const int* __restrict__ lengths, float* __restrict__ out)
{
  __shared__ float sl[256];
  __shared__ float red[256];
  const int b = blockIdx.x, tid = threadIdx.x;
  int lb = lengths[b]; if (lb < 1) lb = 1;
  const float sc = scores[(size_t)tid * 128 + b];
  const bool valid = (tid < lb);
  red[tid] = valid ? sc : -1e30f;
  __syncthreads();
  for (int off = 128; off > 0; off >>= 1) {
    if (tid < off) red[tid] = fmaxf(red[tid], red[tid + off]);
    __syncthreads();
  }
  const float mx = red[0];
  __syncthreads();
  const float p = valid ? __expf(sc - mx) : 0.f;
  red[tid] = p;
  __syncthreads();
  for (int off = 128; off > 0; off >>= 1) {
    if (tid < off) red[tid] += red[tid + off];
    __syncthreads();
  }
  const float inv = 1.f / red[0];
  __syncthreads();
  sl[tid] = p * inv;
  __syncthreads();

  float ax = 0.f, ay = 0.f;
  const int dd = tid * 2;
  for (int t = 0; t < 256; t++) {
    const float w = sl[t];
    if (w != 0.f) {  // wave-uniform
      const float* row = h2 + ((size_t)t * 128 + b) * 512 + dd;
      ax += w * row[0];
      ay += w * row[1];
    }
  }
  float2 r; r.x = ax; r.y = ay;
  *(float2*)(out + (size_t)b * 512 + dd) = r;
}

// ---------------- launch ----------------
extern "C" void kernel_launch(void* const* d_in, const int* in_sizes, int n_in,
                              void* d_out, int out_size, void* d_ws, size_t ws_size,
                              hipStream_t stream) {
  (void)in_sizes; (void)n_in; (void)out_size; (void)ws_size;
  const float* x        = (const float*)d_in[0];
  const int*   lengths  = (const int*)d_in[1];
  const float* w_ih_l0  = (const float*)d_in[2];
  const float* w_hh_l0  = (const float*)d_in[3];
  const float* b_ih_l0  = (const float*)d_in[4];
  const float* b_hh_l0  = (const float*)d_in[5];
  const float* w_ih_l0r = (const float*)d_in[6];
  const float* w_hh_l0r = (const float*)d_in[7];
  const float* b_ih_l0r = (const float*)d_in[8];
  const float* b_hh_l0r = (const float*)d_in[9];
  const float* w_ih_l1  = (const float*)d_in[10];
  const float* w_hh_l1  = (const float*)d_in[11];
  const float* b_ih_l1  = (const float*)d_in[12];
  const float* b_hh_l1  = (const float*)d_in[13];
  const float* w_ih_l1r = (const float*)d_in[14];
  const float* w_hh_l1r = (const float*)d_in[15];
  const float* b_ih_l1r = (const float*)d_in[16];
  const float* b_hh_l1r = (const float*)d_in[17];
  const float* mlp_w    = (const float*)d_in[18];
  const float* mlp_b    = (const float*)d_in[19];
  const float* ctx      = (const float*)d_in[20];
  float* out = (float*)d_out;

  // workspace layout (floats): ~205 MB
  float* ws = (float*)d_ws;
  const size_t XGC  = (size_t)TC * B_ * G4H;          // 8,388,608
  const size_t H_SZ = (size_t)T_ * B_ * H2;           // 16,777,216
  float* xgA    = ws;
  float* xgB    = xgA + XGC;
  float* h1     = xgB + XGC;
  float* h2     = h1 + H_SZ;
  float* hbuf   = h2 + H_SZ;                          // 131,072
  float* cbuf   = hbuf + 131072;                      // 131,072
  float* scores = cbuf + 131072;                      // 32,768
  int*   tags   = (int*)(scores + 32768);             // 2 * 262,144 ints

  // zero scores + both layers' tag arrays (contiguous)
  hipMemsetAsync(scores, 0, (size_t)(32768 + 2 * TAGS_PER_LAYER) * 4, stream);

  dim3 blk(256);
  const dim3 pgrid(G4H / 128, TC, 2);   // (8, 64, 2 directions)

  // layer 0 (K=300), chunked over time
  for (int c = 0; c < T_ / TC; c++) {
    const int t0 = c * TC;
    proj_gemm2<<<pgrid, blk, 0, stream>>>(x, w_ih_l0, w_ih_l0r,
                                          b_ih_l0, b_hh_l0, b_ih_l0r, b_hh_l0r,
                                          xgA, xgB, G4H, D_, lengths, t0);
    lstm_rec<<<256, blk, 0, stream>>>(xgA, xgB, w_hh_l0, w_hh_l0r, lengths, h1,
                                      hbuf, cbuf, tags, t0);
  }
  // layer 1 (K=512)
  for (int c = 0; c < T_ / TC; c++) {
    const int t0 = c * TC;
    proj_gemm2<<<pgrid, blk, 0, stream>>>(h1, w_ih_l1, w_ih_l1r,
                                          b_ih_l1, b_hh_l1, b_ih_l1r, b_hh_l1r,
                                          xgA, xgB, G4H, H2, lengths, t0);
    lstm_rec<<<256, blk, 0, stream>>>(xgA, xgB, w_hh_l1, w_hh_l1r, lengths, h2,
                                      hbuf, cbuf, tags + TAGS_PER_LAYER, t0);
  }
  // attention
  attn_gemm<<<dim3(H2 / 128, (T_ * B_) / 128), blk, 0, stream>>>(h2, mlp_w, mlp_b, ctx, scores, T_ * B_, H2, H2);
  attn_final<<<B_, blk, 0, stream>>>(h2, scores, lengths, out);
}

// Round 7
// 3934.933 us; speedup vs baseline: 7.7868x; 1.3169x over previous
//
#include <hip/hip_runtime.h>

// SentenceEncodingRNN2: 2-layer BiLSTM (T=256,B=128,D=300,H=256) + attention pooling.
// Round 7: data-IS-the-signal sync in lstm_rec. Per-step ring slots pre-filled with
//   NaN sentinel (0xFF memset); producer fires uncached h-store (no waitcnt, no tag);
//   consumers poll the 8 data words until != sentinel. One LLC leg instead of three
//   (drain + tag flight + observe). Chunk handoff via plain-cached bbuf (kernel
//   boundary acquire/release = coherence). Compute left as fp32 VALU to isolate the
//   sync experiment. h is never NaN (sigmoid/tanh of finite inputs) -> no false accept.

#define T_ 256
#define B_ 128
#define D_ 300
#define H_ 256
#define G4H 1024   // 4*H
#define H2 512     // 2*H
#define TC 64      // time-chunk length

// ---------------- helpers ----------------
__device__ __forceinline__ float sigf(float x) { return 1.f / (1.f + __expf(-x)); }
__device__ __forceinline__ float tanhfast(float x) { return 2.f / (1.f + __expf(-2.f * x)) - 1.f; }

// ---------------- dual-direction projection GEMM (chunked, reverse gather) -------
__global__ __launch_bounds__(256) void proj_gemm2(
    const float* __restrict__ X,
    const float* __restrict__ W0, const float* __restrict__ W1,
    const float* __restrict__ b1f, const float* __restrict__ b2f,
    const float* __restrict__ b1r, const float* __restrict__ b2r,
    float* __restrict__ C0, float* __restrict__ C1,
    int N, int K, const int* __restrict__ lengths, int t0)
{
  __shared__ float Xs[16][132];
  __shared__ float Ws[16][132];
  const int rev = blockIdx.z;
  const float* __restrict__ W = rev ? W1 : W0;
  const float* __restrict__ bias1 = rev ? b1r : b1f;
  const float* __restrict__ bias2 = rev ? b2r : b2f;
  float* __restrict__ C = rev ? C1 : C0;

  const int tid = threadIdx.x;
  const int tm = tid & 15, tn = tid >> 4;
  const int m0 = blockIdx.y * 128, n0 = blockIdx.x * 128;
  const int cc = tid & 15, r0 = tid >> 4;
  const int s_step = t0 + blockIdx.y;

  int srow[8];
#pragma unroll
  for (int i = 0; i < 8; i++) {
    const int r = r0 + i * 16;          // r == batch index b within tile
    int ss = s_step;
    if (rev) {
      int lb = lengths[r]; if (lb < 1) lb = 1;
      ss = (s_step < lb) ? (lb - 1 - s_step) : s_step;
    }
    srow[i] = ss * 128 + r;
  }

  float acc[8][8];
#pragma unroll
  for (int i = 0; i < 8; i++)
#pragma unroll
    for (int j = 0; j < 8; j++) acc[i][j] = 0.f;

  float rx[8], rw[8];
  {
    const int k = cc;
    const bool kin = (k < K);
#pragma unroll
    for (int i = 0; i < 8; i++) {
      const int r = r0 + i * 16;
      rx[i] = kin ? X[(size_t)srow[i] * K + k] : 0.f;
      rw[i] = kin ? W[(size_t)(n0 + r) * K + k] : 0.f;
    }
  }

  for (int k0 = 0; k0 < K; k0 += 16) {
#pragma unroll
    for (int i = 0; i < 8; i++) {
      const int r = r0 + i * 16;
      Xs[cc][r] = rx[i];
      Ws[cc][r] = rw[i];
    }
    __syncthreads();
    if (k0 + 16 < K) {
      const int k = k0 + 16 + cc;
      const bool kin = (k < K);
#pragma unroll
      for (int i = 0; i < 8; i++) {
        const int r = r0 + i * 16;
        rx[i] = kin ? X[(size_t)srow[i] * K + k] : 0.f;
        rw[i] = kin ? W[(size_t)(n0 + r) * K + k] : 0.f;
      }
    }
#pragma unroll
    for (int kk = 0; kk < 16; kk++) {
      float a[8], bv[8];
      *(float4*)&a[0] = *(const float4*)&Xs[kk][tm * 8];
      *(float4*)&a[4] = *(const float4*)&Xs[kk][tm * 8 + 4];
      *(float4*)&bv[0] = *(const float4*)&Ws[kk][tn * 8];
      *(float4*)&bv[4] = *(const float4*)&Ws[kk][tn * 8 + 4];
#pragma unroll
      for (int i = 0; i < 8; i++)
#pragma unroll
        for (int j = 0; j < 8; j++) acc[i][j] = fmaf(a[i], bv[j], acc[i][j]);
    }
    __syncthreads();
  }

  const int col0 = n0 + tn * 8;
  float bsum[8];
#pragma unroll
  for (int j = 0; j < 8; j++) bsum[j] = bias1[col0 + j] + bias2[col0 + j];
#pragma unroll
  for (int i = 0; i < 8; i++) {
    float* Crow = C + (size_t)(m0 + tm * 8 + i) * N + col0;
    float4 v0, v1;
    v0.x = acc[i][0] + bsum[0]; v0.y = acc[i][1] + bsum[1];
    v0.z = acc[i][2] + bsum[2]; v0.w = acc[i][3] + bsum[3];
    v1.x = acc[i][4] + bsum[4]; v1.y = acc[i][5] + bsum[5];
    v1.z = acc[i][6] + bsum[6]; v1.w = acc[i][7] + bsum[7];
    *(float4*)(Crow) = v0;
    *(float4*)(Crow + 4) = v1;
  }
}

// ---------------- attention score GEMM with fused tanh*ctx epilogue ----------------
__global__ __launch_bounds__(256) void attn_gemm(
    const float* __restrict__ X, const float* __restrict__ W,
    const float* __restrict__ mlp_b, const float* __restrict__ ctx,
    float* __restrict__ scores, int M, int N, int K)
{
  __shared__ float Xs[16][132];
  __shared__ float Ws[16][132];
  __shared__ float red[128][17];
  const int tid = threadIdx.x;
  const int tm = tid & 15, tn = tid >> 4;
  const int m0 = blockIdx.y * 128, n0 = blockIdx.x * 128;
  const int cc = tid & 15, r0 = tid >> 4;
  float acc[8][8];
#pragma unroll
  for (int i = 0; i < 8; i++)
#pragma unroll
    for (int j = 0; j < 8; j++) acc[i][j] = 0.f;

  for (int k0 = 0; k0 < K; k0 += 16) {
    const int k = k0 + cc;
    const bool kin = (k < K);
#pragma unroll
    for (int i = 0; i < 8; i++) {
      const int r = r0 + i * 16;
      Xs[cc][r] = kin ? X[(size_t)(m0 + r) * K + k] : 0.f;
      Ws[cc][r] = kin ? W[(size_t)(n0 + r) * K + k] : 0.f;
    }
    __syncthreads();
#pragma unroll
    for (int kk = 0; kk < 16; kk++) {
      float a[8], bv[8];
      *(float4*)&a[0] = *(const float4*)&Xs[kk][tm * 8];
      *(float4*)&a[4] = *(const float4*)&Xs[kk][tm * 8 + 4];
      *(float4*)&bv[0] = *(const float4*)&Ws[kk][tn * 8];
      *(float4*)&bv[4] = *(const float4*)&Ws[kk][tn * 8 + 4];
#pragma unroll
      for (int i = 0; i < 8; i++)
#pragma unroll
        for (int j = 0; j < 8; j++) acc[i][j] = fmaf(a[i], bv[j], acc[i][j]);
    }
    __syncthreads();
  }

  const int col0 = n0 + tn * 8;
  float bb8[8], cc8[8];
#pragma unroll
  for (int j = 0; j < 8; j++) { bb8[j] = mlp_b[col0 + j]; cc8[j] = ctx[col0 + j]; }
#pragma unroll
  for (int i = 0; i < 8; i++) {
    float p = 0.f;
#pragma unroll
    for (int j = 0; j < 8; j++) p += tanhfast(acc[i][j] + bb8[j]) * cc8[j];
    red[tm * 8 + i][tn] = p;
  }
  __syncthreads();
  if (tid < 128) {
    float sum = 0.f;
#pragma unroll
    for (int q = 0; q < 16; q++) sum += red[tid][q];
    atomicAdd(&scores[m0 + tid], sum);
  }
}

// ---------------- LSTM recurrence chunk (both directions) ----------------
// blocks: 256 = d(2) * g(16 batch-groups of 8) * s(8 h-slices of 32)
// thread: tid = hh*8 + kc; owns cell (b = g*8+kc, hdim = s*32+hh)
// sync: per-step ring slot pre-filled with 0xFFFFFFFF (-NaN). Producer fires
//   uncached h store (data IS the signal). Consumers poll 8 data words until
//   all != sentinel. Chunk handoff via plain-cached bbuf.
__global__ __launch_bounds__(256, 1) void lstm_rec(
    const float* __restrict__ xgF, const float* __restrict__ xgR,
    const float* __restrict__ whF, const float* __restrict__ whR,
    const int* __restrict__ lengths, float* __restrict__ hout,
    float* __restrict__ ring, float* __restrict__ bbuf, float* __restrict__ cbuf,
    int t0)
{
  // ht: parity double-buffered h_prev tile [8 batches][256],
  // addr(bb,k) = bb*288 + (k>>5)*36 + (k&31)
  __shared__ float ht[2][2304];
  const int tid = threadIdx.x;
  const int blk = blockIdx.x;
  const int d = blk >> 7;
  const int g = (blk >> 3) & 15;
  const int s = blk & 7;
  const int hh = tid >> 3;
  const int kc = tid & 7;
  const int b = g * 8 + kc;
  const int hdim = s * 32 + hh;
  const float* __restrict__ xg = d ? xgR : xgF;
  const float* __restrict__ wh = d ? whR : whF;

  float wreg[4][32];
#pragma unroll
  for (int gate = 0; gate < 4; gate++) {
    const float* wrow = wh + ((size_t)(gate * 256 + hdim)) * 256 + kc * 32;
#pragma unroll
    for (int j = 0; j < 32; j += 4) {
      float4 v = *(const float4*)(wrow + j);
      wreg[gate][j] = v.x; wreg[gate][j + 1] = v.y;
      wreg[gate][j + 2] = v.z; wreg[gate][j + 3] = v.w;
    }
  }

  float c;
  float* ht0 = ht[t0 & 1];
  if (t0 == 0) {
    for (int i = tid; i < 2304; i += 256) ht0[i] = 0.f;
    c = 0.f;
  } else {
    // kernel-boundary acquire/release makes prior chunk's bbuf/cbuf visible.
    const int fi = tid * 8;
    const int b2 = fi >> 8, k2 = fi & 255;
    const float* src = bbuf + ((size_t)d * 128 + g * 8 + b2) * 256 + k2;
    float4 v0 = *(const float4*)(src);
    float4 v1 = *(const float4*)(src + 4);
    float* dst = ht0 + b2 * 288 + ((k2 >> 5) * 36) + (k2 & 31);
    *(float4*)dst = v0;
    *(float4*)(dst + 4) = v1;
    c = cbuf[((size_t)d * 128 + b) * 256 + hdim];
  }
  int lb = lengths[b]; if (lb < 1) lb = 1;
  __syncthreads();

  // prefetch first step's input-projection gates
  const float* xr0 = xg + ((size_t)b) * 1024 + hdim;   // chunk-local step 0
  float x0 = xr0[0], x1 = xr0[256], x2 = xr0[512], x3 = xr0[768];

  const int bb = tid >> 5, kbase = tid & 31;   // consumer: batch-in-group, hh-in-slice

  const int tend = t0 + TC;
  for (int t = t0; t < tend; t++) {
    const float* htr = ht[t & 1];
    float part[4][8];
#pragma unroll
    for (int gate = 0; gate < 4; gate++)
#pragma unroll
      for (int q = 0; q < 8; q++) part[gate][q] = 0.f;

#pragma unroll
    for (int q = 0; q < 8; q++) {
      const float* hrow = htr + q * 288 + kc * 36;
#pragma unroll
      for (int j = 0; j < 32; j += 4) {
        float4 h4 = *(const float4*)(hrow + j);
#pragma unroll
        for (int gate = 0; gate < 4; gate++) {
          float p = part[gate][q];
          p = fmaf(h4.x, wreg[gate][j],     p);
          p = fmaf(h4.y, wreg[gate][j + 1], p);
          p = fmaf(h4.z, wreg[gate][j + 2], p);
          p = fmaf(h4.w, wreg[gate][j + 3], p);
          part[gate][q] = p;
        }
      }
    }

    // halving butterfly over kc: after 3 rounds lane kc holds full sum for q==kc
    float n4[4][4];
#pragma unroll
    for (int gate = 0; gate < 4; gate++)
#pragma unroll
      for (int q = 0; q < 4; q++) {
        const float keep = (kc & 4) ? part[gate][q + 4] : part[gate][q];
        const float send = (kc & 4) ? part[gate][q]     : part[gate][q + 4];
        n4[gate][q] = keep + __shfl_xor(send, 4, 8);
      }
    float n2[4][2];
#pragma unroll
    for (int gate = 0; gate < 4; gate++)
#pragma unroll
      for (int q = 0; q < 2; q++) {
        const float keep = (kc & 2) ? n4[gate][q + 2] : n4[gate][q];
        const float send = (kc & 2) ? n4[gate][q]     : n4[gate][q + 2];
        n2[gate][q] = keep + __shfl_xor(send, 2, 8);
      }
    float gsum[4];
#pragma unroll
    for (int gate = 0; gate < 4; gate++) {
      const float keep = (kc & 1) ? n2[gate][1] : n2[gate][0];
      const float send = (kc & 1) ? n2[gate][0] : n2[gate][1];
      gsum[gate] = keep + __shfl_xor(send, 1, 8);
    }

    const float si = sigf(gsum[0] + x0);
    const float sf = sigf(gsum[1] + x1);
    const float tg = tanhfast(gsum[2] + x2);
    const float so = sigf(gsum[3] + x3);
    c = sf * c + si * tg;
    const float h = so * tanhfast(c);

    const int slot = t - t0;
    if (t < tend - 1) {
      // DATA IS THE SIGNAL: fire uncached store immediately; no waitcnt, no tag.
      __hip_atomic_store(&ring[(((size_t)slot * 2 + d) * 128 + b) * 256 + hdim], h,
                         __ATOMIC_RELAXED, __HIP_MEMORY_SCOPE_AGENT);
    } else {
      // chunk handoff: plain cached store; end-of-kernel release publishes it
      bbuf[((size_t)d * 128 + b) * 256 + hdim] = h;
    }
    const int tin = d ? ((t < lb) ? (lb - 1 - t) : t) : t;
    hout[((size_t)tin * 128 + b) * 512 + d * 256 + hdim] = h;

    if (t < tend - 1) {
      // prefetch next step's xg
      const float* xn = xg + ((size_t)(t + 1 - t0) * 128 + b) * 1024 + hdim;
      const float nx0 = xn[0], nx1 = xn[256], nx2 = xn[512], nx3 = xn[768];

      // consumer: poll the 8 data words directly until none is the sentinel
      const unsigned* srcu = (const unsigned*)(ring +
          (((size_t)slot * 2 + d) * 128 + g * 8 + bb) * 256 + kbase);
      unsigned uv[8];
      int it = 0;
      for (;;) {
        bool ok = true;
#pragma unroll
        for (int j = 0; j < 8; j++) {
          uv[j] = __hip_atomic_load(&srcu[32 * j],
                                    __ATOMIC_RELAXED, __HIP_MEMORY_SCOPE_AGENT);
          ok &= (uv[j] != 0xFFFFFFFFu);
        }
        if (ok || ++it >= 20000) break;   // bounded: failure -> visible absmax
      }

      float* htw = ht[(t + 1) & 1];
#pragma unroll
      for (int j = 0; j < 8; j++)
        htw[bb * 288 + j * 36 + kbase] = __uint_as_float(uv[j]);

      x0 = nx0; x1 = nx1; x2 = nx2; x3 = nx3;
      __syncthreads();   // the ONE barrier per step
    }
  }
  // persist c for next chunk (end-of-kernel release writes back)
  cbuf[((size_t)d * 128 + b) * 256 + hdim] = c;
}

// ---------------- masked softmax over t + weighted sum ----------------
__global__ __launch_bounds__(256) void attn_final(
    const float* __restrict__ h2, const float* __restrict__ scores,
    const int* __restrict__ lengths, float* __restrict__ out)
{
  __shared__ float sl[256];
  __shared__ float red[256];
  const int b = blockIdx.x, tid = threadIdx.x;
  int lb = lengths[b]; if (lb < 1) lb = 1;
  const float sc = scores[(size_t)tid * 128 + b];
  const bool valid = (tid < lb);
  red[tid] = valid ? sc : -1e30f;
  __syncthreads();
  for (int off = 128; off > 0; off >>= 1) {
    if (tid < off) red[tid] = fmaxf(red[tid], red[tid + off]);
    __syncthreads();
  }
  const float mx = red[0];
  __syncthreads();
  const float p = valid ? __expf(sc - mx) : 0.f;
  red[tid] = p;
  __syncthreads();
  for (int off = 128; off > 0; off >>= 1) {
    if (tid < off) red[tid] += red[tid + off];
    __syncthreads();
  }
  const float inv = 1.f / red[0];
  __syncthreads();
  sl[tid] = p * inv;
  __syncthreads();

  float ax = 0.f, ay = 0.f;
  const int dd = tid * 2;
  for (int t = 0; t < 256; t++) {
    const float w = sl[t];
    if (w != 0.f) {  // wave-uniform
      const float* row = h2 + ((size_t)t * 128 + b) * 512 + dd;
      ax += w * row[0];
      ay += w * row[1];
    }
  }
  float2 r; r.x = ax; r.y = ay;
  *(float2*)(out + (size_t)b * 512 + dd) = r;
}

// ---------------- launch ----------------
extern "C" void kernel_launch(void* const* d_in, const int* in_sizes, int n_in,
                              void* d_out, int out_size, void* d_ws, size_t ws_size,
                              hipStream_t stream) {
  (void)in_sizes; (void)n_in; (void)out_size; (void)ws_size;
  const float* x        = (const float*)d_in[0];
  const int*   lengths  = (const int*)d_in[1];
  const float* w_ih_l0  = (const float*)d_in[2];
  const float* w_hh_l0  = (const float*)d_in[3];
  const float* b_ih_l0  = (const float*)d_in[4];
  const float* b_hh_l0  = (const float*)d_in[5];
  const float* w_ih_l0r = (const float*)d_in[6];
  const float* w_hh_l0r = (const float*)d_in[7];
  const float* b_ih_l0r = (const float*)d_in[8];
  const float* b_hh_l0r = (const float*)d_in[9];
  const float* w_ih_l1  = (const float*)d_in[10];
  const float* w_hh_l1  = (const float*)d_in[11];
  const float* b_ih_l1  = (const float*)d_in[12];
  const float* b_hh_l1  = (const float*)d_in[13];
  const float* w_ih_l1r = (const float*)d_in[14];
  const float* w_hh_l1r = (const float*)d_in[15];
  const float* b_ih_l1r = (const float*)d_in[16];
  const float* b_hh_l1r = (const float*)d_in[17];
  const float* mlp_w    = (const float*)d_in[18];
  const float* mlp_b    = (const float*)d_in[19];
  const float* ctx      = (const float*)d_in[20];
  float* out = (float*)d_out;

  // workspace layout (floats): ~219 MB
  float* ws = (float*)d_ws;
  const size_t XGC    = (size_t)TC * B_ * G4H;        // 8,388,608
  const size_t H_SZ   = (size_t)T_ * B_ * H2;         // 16,777,216
  const size_t RINGSZ = (size_t)TC * 2 * B_ * H_;     // 4,194,304 floats = 16 MB
  float* xgA    = ws;
  float* xgB    = xgA + XGC;
  float* h1     = xgB + XGC;
  float* h2     = h1 + H_SZ;
  float* ring   = h2 + H_SZ;
  float* bbuf   = ring + RINGSZ;                      // 65,536
  float* cbuf   = bbuf + 65536;                       // 65,536
  float* scores = cbuf + 65536;                       // 32,768

  hipMemsetAsync(scores, 0, 32768 * 4, stream);

  dim3 blk(256);
  const dim3 pgrid(G4H / 128, TC, 2);   // (8, 64, 2 directions)

  // layer 0 (K=300), chunked over time
  for (int c = 0; c < T_ / TC; c++) {
    const int t0 = c * TC;
    proj_gemm2<<<pgrid, blk, 0, stream>>>(x, w_ih_l0, w_ih_l0r,
                                          b_ih_l0, b_hh_l0, b_ih_l0r, b_hh_l0r,
                                          xgA, xgB, G4H, D_, lengths, t0);
    hipMemsetAsync(ring, 0xFF, RINGSZ * 4, stream);   // sentinel = 0xFFFFFFFF (-NaN)
    lstm_rec<<<256, blk, 0, stream>>>(xgA, xgB, w_hh_l0, w_hh_l0r, lengths, h1,
                                      ring, bbuf, cbuf, t0);
  }
  // layer 1 (K=512)
  for (int c = 0; c < T_ / TC; c++) {
    const int t0 = c * TC;
    proj_gemm2<<<pgrid, blk, 0, stream>>>(h1, w_ih_l1, w_ih_l1r,
                                          b_ih_l1, b_hh_l1, b_ih_l1r, b_hh_l1r,
                                          xgA, xgB, G4H, H2, lengths, t0);
    hipMemsetAsync(ring, 0xFF, RINGSZ * 4, stream);
    lstm_rec<<<256, blk, 0, stream>>>(xgA, xgB, w_hh_l1, w_hh_l1r, lengths, h2,
                                      ring, bbuf, cbuf, t0);
  }
  // attention
  attn_gemm<<<dim3(H2 / 128, (T_ * B_) / 128), blk, 0, stream>>>(h2, mlp_w, mlp_b, ctx, scores, T_ * B_, H2, H2);
  attn_final<<<B_, blk, 0, stream>>>(h2, scores, lengths, out);
}

// Round 9
// 2965.344 us; speedup vs baseline: 10.3329x; 1.3270x over previous
//
#include <hip/hip_runtime.h>

// SentenceEncodingRNN2: 2-layer BiLSTM (T=256,B=128,D=300,H=256) + attention pooling.
// Round 9: split-bf16 MFMA GEMMs (proj + attn) -- round-8 retry with the compile fix
//   (value-returning hi/lo split; vector elements can't bind to short&).
//   fp32 = hi(bf16) + lo(bf16); C = Ah*Bh + Ah*Bl + Al*Bh via mfma_f32_16x16x32_bf16
//   (err ~2^-17, safe vs 2.89e-3). 128x128 tile, 4 waves (2x2 of 64x64), 4x4 MFMA
//   tiles/wave, LDS k-stride 40 (<=2-way bank aliasing, free per m136). attn
//   epilogue: in-register tanh*ctx + 16-lane shuffle reduce.
//   R7 counters: attn_gemm 300us @ MfmaUtil=0/VALU 47%/2.1e7 conflicts; proj ~1.0ms.
//   lstm_rec (R7 data-is-signal sync, ~283us/dispatch) untouched.

#define T_ 256
#define B_ 128
#define D_ 300
#define H_ 256
#define G4H 1024   // 4*H
#define H2 512     // 2*H
#define TC 64      // time-chunk length
#define LDK 40     // LDS k-stride in bf16 elements (80 B rows: 16B-aligned frags)

typedef __attribute__((ext_vector_type(8))) short bf16x8;
typedef __attribute__((ext_vector_type(4))) short short4v;
typedef __attribute__((ext_vector_type(4))) float f32x4;

// ---------------- helpers ----------------
__device__ __forceinline__ float sigf(float x) { return 1.f / (1.f + __expf(-x)); }
__device__ __forceinline__ float tanhfast(float x) { return 2.f / (1.f + __expf(-2.f * x)) - 1.f; }

// hi/lo bf16 split of fp32 (truncation; lo captures the residual)
__device__ __forceinline__ short hi_bf16(float x) {
  return (short)(__float_as_uint(x) >> 16);
}
__device__ __forceinline__ short lo_bf16(float x) {
  float lo = x - __uint_as_float(__float_as_uint(x) & 0xFFFF0000u);
  return (short)(__float_as_uint(lo) >> 16);
}

__device__ __forceinline__ void split_f4(const float4 v, short* hp, short* lp) {
  short4v h, l;
  h.x = hi_bf16(v.x); l.x = lo_bf16(v.x);
  h.y = hi_bf16(v.y); l.y = lo_bf16(v.y);
  h.z = hi_bf16(v.z); l.z = lo_bf16(v.z);
  h.w = hi_bf16(v.w); l.w = lo_bf16(v.w);
  *(short4v*)hp = h;
  *(short4v*)lp = l;
}

// ---------------- dual-direction projection GEMM, split-bf16 MFMA ----------------
// C[lm][n] = sum_k X[srow(lm)][k]*W[n][k] + b1[n]+b2[n]; lm = chunk-local scan index.
// grid: (N/128, TC, 2 dirs); block 256 = 4 waves in 2x2 (64x64 each).
__global__ __launch_bounds__(256, 2) void proj_gemm2(
    const float* __restrict__ X,
    const float* __restrict__ W0, const float* __restrict__ W1,
    const float* __restrict__ b1f, const float* __restrict__ b2f,
    const float* __restrict__ b1r, const float* __restrict__ b2r,
    float* __restrict__ C0, float* __restrict__ C1,
    int N, int K, const int* __restrict__ lengths, int t0)
{
  __shared__ short Xh[128 * LDK], Xl[128 * LDK];
  __shared__ short Wh[128 * LDK], Wl[128 * LDK];
  const int rev = blockIdx.z;
  const float* __restrict__ W = rev ? W1 : W0;
  const float* __restrict__ bias1 = rev ? b1r : b1f;
  const float* __restrict__ bias2 = rev ? b2r : b2f;
  float* __restrict__ C = rev ? C1 : C0;

  const int tid = threadIdx.x;
  const int m0 = blockIdx.y * 128, n0 = blockIdx.x * 128;
  const int s_step = t0 + blockIdx.y;

  // staging: thread covers rows sr+32p, cols sc..sc+3 of the 128x32 k-tile
  const int sr = tid >> 3;
  const int sc = (tid & 7) * 4;
  const float* px[4];
  const float* pw[4];
#pragma unroll
  for (int p = 0; p < 4; p++) {
    const int r = sr + p * 32;          // r == batch index within tile
    int ss = s_step;
    if (rev) {
      int lb = lengths[r]; if (lb < 1) lb = 1;
      ss = (s_step < lb) ? (lb - 1 - s_step) : s_step;
    }
    px[p] = X + (size_t)(ss * 128 + r) * K;
    pw[p] = W + (size_t)(n0 + r) * K;
  }

  const int lane = tid & 63, w = tid >> 6;
  const int mb = (w & 1) * 64, nb = (w >> 1) * 64;
  const int r16 = lane & 15, quad = lane >> 4;

  f32x4 acc[4][4];
#pragma unroll
  for (int i = 0; i < 4; i++)
#pragma unroll
    for (int j = 0; j < 4; j++) acc[i][j] = (f32x4){0.f, 0.f, 0.f, 0.f};

  for (int k0 = 0; k0 < K; k0 += 32) {
    const int gk = k0 + sc;
    const bool kin = (gk < K);          // K % 4 == 0 -> whole float4 in/out
#pragma unroll
    for (int p = 0; p < 4; p++) {
      float4 xv = {0.f, 0.f, 0.f, 0.f}, wv = {0.f, 0.f, 0.f, 0.f};
      if (kin) { xv = *(const float4*)(px[p] + gk); wv = *(const float4*)(pw[p] + gk); }
      const int ro = (sr + p * 32) * LDK + sc;
      split_f4(xv, &Xh[ro], &Xl[ro]);
      split_f4(wv, &Wh[ro], &Wl[ro]);
    }
    __syncthreads();

    bf16x8 ah[4], al[4], bh[4], bl[4];
#pragma unroll
    for (int mt = 0; mt < 4; mt++) {
      const int ro = (mb + mt * 16 + r16) * LDK + quad * 8;
      ah[mt] = *(const bf16x8*)&Xh[ro];
      al[mt] = *(const bf16x8*)&Xl[ro];
    }
#pragma unroll
    for (int nt = 0; nt < 4; nt++) {
      const int ro = (nb + nt * 16 + r16) * LDK + quad * 8;
      bh[nt] = *(const bf16x8*)&Wh[ro];
      bl[nt] = *(const bf16x8*)&Wl[ro];
    }
#pragma unroll
    for (int mt = 0; mt < 4; mt++)
#pragma unroll
      for (int nt = 0; nt < 4; nt++) {
        acc[mt][nt] = __builtin_amdgcn_mfma_f32_16x16x32_bf16(ah[mt], bh[nt], acc[mt][nt], 0, 0, 0);
        acc[mt][nt] = __builtin_amdgcn_mfma_f32_16x16x32_bf16(ah[mt], bl[nt], acc[mt][nt], 0, 0, 0);
        acc[mt][nt] = __builtin_amdgcn_mfma_f32_16x16x32_bf16(al[mt], bh[nt], acc[mt][nt], 0, 0, 0);
      }
    __syncthreads();
  }

  // epilogue: C/D layout row = quad*4+reg (m), col = lane&15 (n)  [m89-verified]
  float bsum[4];
#pragma unroll
  for (int nt = 0; nt < 4; nt++) {
    const int col = n0 + nb + nt * 16 + r16;
    bsum[nt] = bias1[col] + bias2[col];
  }
#pragma unroll
  for (int mt = 0; mt < 4; mt++) {
    const int row = m0 + mb + mt * 16 + quad * 4;
#pragma unroll
    for (int nt = 0; nt < 4; nt++) {
      const int col = n0 + nb + nt * 16 + r16;
      float* Cp = C + (size_t)row * N + col;
#pragma unroll
      for (int reg = 0; reg < 4; reg++)
        Cp[(size_t)reg * N] = acc[mt][nt][reg] + bsum[nt];
    }
  }
}

// ---------------- attention score GEMM, split-bf16 MFMA, fused tanh*ctx ----------
// scores[m] += sum_n tanh(h2[m]@mlp_w^T + b)[n] * ctx[n]
__global__ __launch_bounds__(256, 2) void attn_gemm(
    const float* __restrict__ X, const float* __restrict__ W,
    const float* __restrict__ mlp_b, const float* __restrict__ ctx,
    float* __restrict__ scores, int M, int N, int K)
{
  __shared__ short Xh[128 * LDK], Xl[128 * LDK];
  __shared__ short Wh[128 * LDK], Wl[128 * LDK];
  const int tid = threadIdx.x;
  const int m0 = blockIdx.y * 128, n0 = blockIdx.x * 128;

  const int sr = tid >> 3;
  const int sc = (tid & 7) * 4;
  const float* px[4];
  const float* pw[4];
#pragma unroll
  for (int p = 0; p < 4; p++) {
    px[p] = X + (size_t)(m0 + sr + p * 32) * K;
    pw[p] = W + (size_t)(n0 + sr + p * 32) * K;
  }

  const int lane = tid & 63, w = tid >> 6;
  const int mb = (w & 1) * 64, nb = (w >> 1) * 64;
  const int r16 = lane & 15, quad = lane >> 4;

  f32x4 acc[4][4];
#pragma unroll
  for (int i = 0; i < 4; i++)
#pragma unroll
    for (int j = 0; j < 4; j++) acc[i][j] = (f32x4){0.f, 0.f, 0.f, 0.f};

  for (int k0 = 0; k0 < K; k0 += 32) {
    const int gk = k0 + sc;
#pragma unroll
    for (int p = 0; p < 4; p++) {
      float4 xv = *(const float4*)(px[p] + gk);
      float4 wv = *(const float4*)(pw[p] + gk);
      const int ro = (sr + p * 32) * LDK + sc;
      split_f4(xv, &Xh[ro], &Xl[ro]);
      split_f4(wv, &Wh[ro], &Wl[ro]);
    }
    __syncthreads();

    bf16x8 ah[4], al[4], bh[4], bl[4];
#pragma unroll
    for (int mt = 0; mt < 4; mt++) {
      const int ro = (mb + mt * 16 + r16) * LDK + quad * 8;
      ah[mt] = *(const bf16x8*)&Xh[ro];
      al[mt] = *(const bf16x8*)&Xl[ro];
    }
#pragma unroll
    for (int nt = 0; nt < 4; nt++) {
      const int ro = (nb + nt * 16 + r16) * LDK + quad * 8;
      bh[nt] = *(const bf16x8*)&Wh[ro];
      bl[nt] = *(const bf16x8*)&Wl[ro];
    }
#pragma unroll
    for (int mt = 0; mt < 4; mt++)
#pragma unroll
      for (int nt = 0; nt < 4; nt++) {
        acc[mt][nt] = __builtin_amdgcn_mfma_f32_16x16x32_bf16(ah[mt], bh[nt], acc[mt][nt], 0, 0, 0);
        acc[mt][nt] = __builtin_amdgcn_mfma_f32_16x16x32_bf16(ah[mt], bl[nt], acc[mt][nt], 0, 0, 0);
        acc[mt][nt] = __builtin_amdgcn_mfma_f32_16x16x32_bf16(al[mt], bh[nt], acc[mt][nt], 0, 0, 0);
      }
    __syncthreads();
  }

  // epilogue: tanh(acc + b)*ctx, reduce over n (4 nt in-thread, then 16 lanes)
  float bb4[4], cc4[4];
#pragma unroll
  for (int nt = 0; nt < 4; nt++) {
    const int col = n0 + nb + nt * 16 + r16;
    bb4[nt] = mlp_b[col];
    cc4[nt] = ctx[col];
  }
#pragma unroll
  for (int mt = 0; mt < 4; mt++) {
#pragma unroll
    for (int reg = 0; reg < 4; reg++) {
      float ssum = 0.f;
#pragma unroll
      for (int nt = 0; nt < 4; nt++)
        ssum += tanhfast(acc[mt][nt][reg] + bb4[nt]) * cc4[nt];
      ssum += __shfl_xor(ssum, 1);
      ssum += __shfl_xor(ssum, 2);
      ssum += __shfl_xor(ssum, 4);
      ssum += __shfl_xor(ssum, 8);
      if (r16 == 0)
        atomicAdd(&scores[m0 + mb + mt * 16 + quad * 4 + reg], ssum);
    }
  }
}

// ---------------- LSTM recurrence chunk (both directions) -- unchanged R7 --------
// blocks: 256 = d(2) * g(16 batch-groups of 8) * s(8 h-slices of 32)
// thread: tid = hh*8 + kc; owns cell (b = g*8+kc, hdim = s*32+hh)
__global__ __launch_bounds__(256, 1) void lstm_rec(
    const float* __restrict__ xgF, const float* __restrict__ xgR,
    const float* __restrict__ whF, const float* __restrict__ whR,
    const int* __restrict__ lengths, float* __restrict__ hout,
    float* __restrict__ ring, float* __restrict__ bbuf, float* __restrict__ cbuf,
    int t0)
{
  __shared__ float ht[2][2304];
  const int tid = threadIdx.x;
  const int blk = blockIdx.x;
  const int d = blk >> 7;
  const int g = (blk >> 3) & 15;
  const int s = blk & 7;
  const int hh = tid >> 3;
  const int kc = tid & 7;
  const int b = g * 8 + kc;
  const int hdim = s * 32 + hh;
  const float* __restrict__ xg = d ? xgR : xgF;
  const float* __restrict__ wh = d ? whR : whF;

  float wreg[4][32];
#pragma unroll
  for (int gate = 0; gate < 4; gate++) {
    const float* wrow = wh + ((size_t)(gate * 256 + hdim)) * 256 + kc * 32;
#pragma unroll
    for (int j = 0; j < 32; j += 4) {
      float4 v = *(const float4*)(wrow + j);
      wreg[gate][j] = v.x; wreg[gate][j + 1] = v.y;
      wreg[gate][j + 2] = v.z; wreg[gate][j + 3] = v.w;
    }
  }

  float c;
  float* ht0 = ht[t0 & 1];
  if (t0 == 0) {
    for (int i = tid; i < 2304; i += 256) ht0[i] = 0.f;
    c = 0.f;
  } else {
    const int fi = tid * 8;
    const int b2 = fi >> 8, k2 = fi & 255;
    const float* src = bbuf + ((size_t)d * 128 + g * 8 + b2) * 256 + k2;
    float4 v0 = *(const float4*)(src);
    float4 v1 = *(const float4*)(src + 4);
    float* dst = ht0 + b2 * 288 + ((k2 >> 5) * 36) + (k2 & 31);
    *(float4*)dst = v0;
    *(float4*)(dst + 4) = v1;
    c = cbuf[((size_t)d * 128 + b) * 256 + hdim];
  }
  int lb = lengths[b]; if (lb < 1) lb = 1;
  __syncthreads();

  const float* xr0 = xg + ((size_t)b) * 1024 + hdim;
  float x0 = xr0[0], x1 = xr0[256], x2 = xr0[512], x3 = xr0[768];

  const int bb = tid >> 5, kbase = tid & 31;

  const int tend = t0 + TC;
  for (int t = t0; t < tend; t++) {
    const float* htr = ht[t & 1];
    float part[4][8];
#pragma unroll
    for (int gate = 0; gate < 4; gate++)
#pragma unroll
      for (int q = 0; q < 8; q++) part[gate][q] = 0.f;

#pragma unroll
    for (int q = 0; q < 8; q++) {
      const float* hrow = htr + q * 288 + kc * 36;
#pragma unroll
      for (int j = 0; j < 32; j += 4) {
        float4 h4 = *(const float4*)(hrow + j);
#pragma unroll
        for (int gate = 0; gate < 4; gate++) {
          float p = part[gate][q];
          p = fmaf(h4.x, wreg[gate][j],     p);
          p = fmaf(h4.y, wreg[gate][j + 1], p);
          p = fmaf(h4.z, wreg[gate][j + 2], p);
          p = fmaf(h4.w, wreg[gate][j + 3], p);
          part[gate][q] = p;
        }
      }
    }

    float n4[4][4];
#pragma unroll
    for (int gate = 0; gate < 4; gate++)
#pragma unroll
      for (int q = 0; q < 4; q++) {
        const float keep = (kc & 4) ? part[gate][q + 4] : part[gate][q];
        const float send = (kc & 4) ? part[gate][q]     : part[gate][q + 4];
        n4[gate][q] = keep + __shfl_xor(send, 4, 8);
      }
    float n2[4][2];
#pragma unroll
    for (int gate = 0; gate < 4; gate++)
#pragma unroll
      for (int q = 0; q < 2; q++) {
        const float keep = (kc & 2) ? n4[gate][q + 2] : n4[gate][q];
        const float send = (kc & 2) ? n4[gate][q]     : n4[gate][q + 2];
        n2[gate][q] = keep + __shfl_xor(send, 2, 8);
      }
    float gsum[4];
#pragma unroll
    for (int gate = 0; gate < 4; gate++) {
      const float keep = (kc & 1) ? n2[gate][1] : n2[gate][0];
      const float send = (kc & 1) ? n2[gate][0] : n2[gate][1];
      gsum[gate] = keep + __shfl_xor(send, 1, 8);
    }

    const float si = sigf(gsum[0] + x0);
    const float sf = sigf(gsum[1] + x1);
    const float tg = tanhfast(gsum[2] + x2);
    const float so = sigf(gsum[3] + x3);
    c = sf * c + si * tg;
    const float h = so * tanhfast(c);

    const int slot = t - t0;
    if (t < tend - 1) {
      __hip_atomic_store(&ring[(((size_t)slot * 2 + d) * 128 + b) * 256 + hdim], h,
                         __ATOMIC_RELAXED, __HIP_MEMORY_SCOPE_AGENT);
    } else {
      bbuf[((size_t)d * 128 + b) * 256 + hdim] = h;
    }
    const int tin = d ? ((t < lb) ? (lb - 1 - t) : t) : t;
    hout[((size_t)tin * 128 + b) * 512 + d * 256 + hdim] = h;

    if (t < tend - 1) {
      const float* xn = xg + ((size_t)(t + 1 - t0) * 128 + b) * 1024 + hdim;
      const float nx0 = xn[0], nx1 = xn[256], nx2 = xn[512], nx3 = xn[768];

      const unsigned* srcu = (const unsigned*)(ring +
          (((size_t)slot * 2 + d) * 128 + g * 8 + bb) * 256 + kbase);
      unsigned uv[8];
      int it = 0;
      for (;;) {
        bool ok = true;
#pragma unroll
        for (int j = 0; j < 8; j++) {
          uv[j] = __hip_atomic_load(&srcu[32 * j],
                                    __ATOMIC_RELAXED, __HIP_MEMORY_SCOPE_AGENT);
          ok &= (uv[j] != 0xFFFFFFFFu);
        }
        if (ok || ++it >= 20000) break;
      }

      float* htw = ht[(t + 1) & 1];
#pragma unroll
      for (int j = 0; j < 8; j++)
        htw[bb * 288 + j * 36 + kbase] = __uint_as_float(uv[j]);

      x0 = nx0; x1 = nx1; x2 = nx2; x3 = nx3;
      __syncthreads();
    }
  }
  cbuf[((size_t)d * 128 + b) * 256 + hdim] = c;
}

// ---------------- masked softmax over t + weighted sum ----------------
__global__ __launch_bounds__(256) void attn_final(
    const float* __restrict__ h2, const float* __restrict__ scores,
    const int* __restrict__ lengths, float* __restrict__ out)
{
  __shared__ float sl[256];
  __shared__ float red[256];
  const int b = blockIdx.x, tid = threadIdx.x;
  int lb = lengths[b]; if (lb < 1) lb = 1;
  const float sc = scores[(size_t)tid * 128 + b];
  const bool valid = (tid < lb);
  red[tid] = valid ? sc : -1e30f;
  __syncthreads();
  for (int off = 128; off > 0; off >>= 1) {
    if (tid < off) red[tid] = fmaxf(red[tid], red[tid + off]);
    __syncthreads();
  }
  const float mx = red[0];
  __syncthreads();
  const float p = valid ? __expf(sc - mx) : 0.f;
  red[tid] = p;
  __syncthreads();
  for (int off = 128; off > 0; off >>= 1) {
    if (tid < off) red[tid] += red[tid + off];
    __syncthreads();
  }
  const float inv = 1.f / red[0];
  __syncthreads();
  sl[tid] = p * inv;
  __syncthreads();

  float ax = 0.f, ay = 0.f;
  const int dd = tid * 2;
  for (int t = 0; t < 256; t++) {
    const float w = sl[t];
    if (w != 0.f) {
      const float* row = h2 + ((size_t)t * 128 + b) * 512 + dd;
      ax += w * row[0];
      ay += w * row[1];
    }
  }
  float2 r; r.x = ax; r.y = ay;
  *(float2*)(out + (size_t)b * 512 + dd) = r;
}

// ---------------- launch ----------------
extern "C" void kernel_launch(void* const* d_in, const int* in_sizes, int n_in,
                              void* d_out, int out_size, void* d_ws, size_t ws_size,
                              hipStream_t stream) {
  (void)in_sizes; (void)n_in; (void)out_size; (void)ws_size;
  const float* x        = (const float*)d_in[0];
  const int*   lengths  = (const int*)d_in[1];
  const float* w_ih_l0  = (const float*)d_in[2];
  const float* w_hh_l0  = (const float*)d_in[3];
  const float* b_ih_l0  = (const float*)d_in[4];
  const float* b_hh_l0  = (const float*)d_in[5];
  const float* w_ih_l0r = (const float*)d_in[6];
  const float* w_hh_l0r = (const float*)d_in[7];
  const float* b_ih_l0r = (const float*)d_in[8];
  const float* b_hh_l0r = (const float*)d_in[9];
  const float* w_ih_l1  = (const float*)d_in[10];
  const float* w_hh_l1  = (const float*)d_in[11];
  const float* b_ih_l1  = (const float*)d_in[12];
  const float* b_hh_l1  = (const float*)d_in[13];
  const float* w_ih_l1r = (const float*)d_in[14];
  const float* w_hh_l1r = (const float*)d_in[15];
  const float* b_ih_l1r = (const float*)d_in[16];
  const float* b_hh_l1r = (const float*)d_in[17];
  const float* mlp_w    = (const float*)d_in[18];
  const float* mlp_b    = (const float*)d_in[19];
  const float* ctx      = (const float*)d_in[20];
  float* out = (float*)d_out;

  // workspace layout (floats): ~219 MB
  float* ws = (float*)d_ws;
  const size_t XGC    = (size_t)TC * B_ * G4H;        // 8,388,608
  const size_t H_SZ   = (size_t)T_ * B_ * H2;         // 16,777,216
  const size_t RINGSZ = (size_t)TC * 2 * B_ * H_;     // 4,194,304 floats = 16 MB
  float* xgA    = ws;
  float* xgB    = xgA + XGC;
  float* h1     = xgB + XGC;
  float* h2     = h1 + H_SZ;
  float* ring   = h2 + H_SZ;
  float* bbuf   = ring + RINGSZ;                      // 65,536
  float* cbuf   = bbuf + 65536;                       // 65,536
  float* scores = cbuf + 65536;                       // 32,768

  (void)hipMemsetAsync(scores, 0, 32768 * 4, stream);

  dim3 blk(256);
  const dim3 pgrid(G4H / 128, TC, 2);   // (8, 64, 2 directions)

  // layer 0 (K=300), chunked over time
  for (int c = 0; c < T_ / TC; c++) {
    const int t0 = c * TC;
    proj_gemm2<<<pgrid, blk, 0, stream>>>(x, w_ih_l0, w_ih_l0r,
                                          b_ih_l0, b_hh_l0, b_ih_l0r, b_hh_l0r,
                                          xgA, xgB, G4H, D_, lengths, t0);
    (void)hipMemsetAsync(ring, 0xFF, RINGSZ * 4, stream);   // sentinel = 0xFFFFFFFF
    lstm_rec<<<256, blk, 0, stream>>>(xgA, xgB, w_hh_l0, w_hh_l0r, lengths, h1,
                                      ring, bbuf, cbuf, t0);
  }
  // layer 1 (K=512)
  for (int c = 0; c < T_ / TC; c++) {
    const int t0 = c * TC;
    proj_gemm2<<<pgrid, blk, 0, stream>>>(h1, w_ih_l1, w_ih_l1r,
                                          b_ih_l1, b_hh_l1, b_ih_l1r, b_hh_l1r,
                                          xgA, xgB, G4H, H2, lengths, t0);
    (void)hipMemsetAsync(ring, 0xFF, RINGSZ * 4, stream);
    lstm_rec<<<256, blk, 0, stream>>>(xgA, xgB, w_hh_l1, w_hh_l1r, lengths, h2,
                                      ring, bbuf, cbuf, t0);
  }
  // attention (M=32768, N=512, K=512)
  attn_gemm<<<dim3(H2 / 128, (T_ * B_) / 128), blk, 0, stream>>>(h2, mlp_w, mlp_b, ctx, scores, T_ * B_, H2, H2);
  attn_final<<<B_, blk, 0, stream>>>(h2, scores, lengths, out);
}